// Round 1
// baseline (2726.611 us; speedup 1.0000x reference)
//
#include <hip/hip_runtime.h>
#include <stdint.h>

#define S_LEN 2048
#define NH 16
#define DK 64
#define DM 1024
#define NB_DELTA (2*S_LEN-1)   // 4095

typedef __attribute__((ext_vector_type(8))) __bf16 bf16x8;
typedef __attribute__((ext_vector_type(4))) float f32x4;

__device__ __forceinline__ unsigned short f2bf(float f){
    union { float f; unsigned int u; } v; v.f = f;
    unsigned int u = v.u;
    return (unsigned short)((u + 0x7FFFu + ((u >> 16) & 1u)) >> 16);
}

// ---------------- bias table: biasT[h][delta+2047] = rel_bias[bucket(delta)][h]
__global__ __launch_bounds__(256) void bias_table_kernel(const float* __restrict__ rel_bias,
                                                         float* __restrict__ biasT){
    int t = blockIdx.x * blockDim.x + threadIdx.x;
    if (t >= NB_DELTA) return;
    int delta = t - (S_LEN - 1);          // j - i
    int bucket = (delta > 0) ? 16 : 0;
    int a = delta < 0 ? -delta : delta;
    int b;
    if (a < 8) b = a;
    else {
        int bl = 33 - __builtin_clz(a * a);   // 8 + floor(2*log2(a/8)), exact
        b = bl < 15 ? bl : 15;
    }
    bucket += b;
    for (int h = 0; h < NH; h++)
        biasT[h * NB_DELTA + t] = rel_bias[bucket * NH + h];
}

// ---------------- fp32 -> bf16 cast (n divisible by 4)
__global__ __launch_bounds__(256) void cast_bf16_kernel(const float* __restrict__ in,
                                                        unsigned short* __restrict__ out, int n){
    int i = (blockIdx.x * blockDim.x + threadIdx.x) * 4;
    if (i >= n) return;
    float4 f = *(const float4*)(in + i);
    ushort4 o;
    o.x = f2bf(f.x); o.y = f2bf(f.y); o.z = f2bf(f.z); o.w = f2bf(f.w);
    *(ushort4*)(out + i) = o;
}

// ---------------- transpose + cast: dst[n][1024] = bf16(src[k][n]), 1024x1024
__global__ __launch_bounds__(256) void transpose_cast_kernel(const float* __restrict__ src,
                                                             unsigned short* __restrict__ dst){
    __shared__ float tile[32][33];
    int bx = blockIdx.x, by = blockIdx.y;
    int tx = threadIdx.x & 31, ty = threadIdx.x >> 5;   // ty 0..7
    for (int i = 0; i < 4; i++)
        tile[ty + 8*i][tx] = src[(size_t)(by*32 + ty + 8*i) * 1024 + bx*32 + tx];
    __syncthreads();
    for (int i = 0; i < 4; i++)
        dst[(size_t)(bx*32 + ty + 8*i) * 1024 + by*32 + tx] = f2bf(tile[tx][ty + 8*i]);
}

// ---------------- bf16 MFMA GEMM: C[m][n] = sum_k A[m][k] * BT[n][k]
// BM=BN=128, BK=32, 256 threads (4 waves, 2x2 of 64x64)
#define GLDS 40   // padded K-stride in bf16 elems (32 + 8)
__global__ __launch_bounds__(256) void gemm_bt_kernel(const unsigned short* __restrict__ A,
                                                      const unsigned short* __restrict__ BT,
                                                      float* __restrict__ C,
                                                      int Kdim, int ldc){
    __shared__ __align__(16) unsigned short As[128 * GLDS];
    __shared__ __align__(16) unsigned short Bs[128 * GLDS];
    int t = threadIdx.x;
    int wave = t >> 6, lane = t & 63;
    int quad = lane >> 4, l16 = lane & 15;
    int wm = (wave >> 1) * 64, wn = (wave & 1) * 64;
    size_t row0 = (size_t)blockIdx.y * 128, col0 = (size_t)blockIdx.x * 128;

    f32x4 acc[4][4] = {};

    for (int kt = 0; kt < Kdim; kt += 32) {
        for (int s = 0; s < 2; s++) {
            int g = t + s * 256;           // 512 granules of 8 bf16
            int r = g >> 2, kg = (g & 3) * 8;
            *(int4*)(&As[r * GLDS + kg]) = *(const int4*)(A + (row0 + r) * Kdim + kt + kg);
            *(int4*)(&Bs[r * GLDS + kg]) = *(const int4*)(BT + (col0 + r) * Kdim + kt + kg);
        }
        __syncthreads();
        bf16x8 a[4], b[4];
        for (int i = 0; i < 4; i++)
            a[i] = *(const bf16x8*)(&As[(wm + i*16 + l16) * GLDS + quad * 8]);
        for (int j = 0; j < 4; j++)
            b[j] = *(const bf16x8*)(&Bs[(wn + j*16 + l16) * GLDS + quad * 8]);
        for (int i = 0; i < 4; i++)
            for (int j = 0; j < 4; j++)
                acc[i][j] = __builtin_amdgcn_mfma_f32_16x16x32_bf16(a[i], b[j], acc[i][j], 0, 0, 0);
        __syncthreads();
    }
    // C/D layout: col = lane&15, row = quad*4 + reg
    for (int i = 0; i < 4; i++)
        for (int j = 0; j < 4; j++) {
            size_t r0 = row0 + wm + i*16 + quad*4;
            size_t c  = col0 + wn + j*16 + l16;
            for (int r = 0; r < 4; r++)
                C[(r0 + r) * ldc + c] = acc[i][j][r];
        }
}

// ---------------- flash attention (fp32, LDS-tiled), writes bf16 ctx
// grid: (S/16, H, B), 256 threads. qkv fused rows of 3072: [q | k | v]
__global__ __launch_bounds__(256) void flash_kernel(const float* __restrict__ qkv,
                                                    const float* __restrict__ biasT,
                                                    unsigned short* __restrict__ ctx_bf16){
    int qt = blockIdx.x, h = blockIdx.y, b = blockIdx.z;
    int t = threadIdx.x;
    int d = t & 63;        // lane within wave
    int qg = t >> 6;       // wave id 0..3

    __shared__ float Qs[16][64];
    __shared__ float Ks[64][68];
    __shared__ float Vs[64][68];
    __shared__ float P[16][64];
    __shared__ float m_s[16], l_s[16], mnew_s[16], al_s[16];
    __shared__ float part[16][4];

    // load Q tile (16 x 64)
    {
        int r = t >> 4, c = (t & 15) * 4;
        const float* src = qkv + ((size_t)(b * S_LEN + qt * 16 + r)) * 3072 + h * 64 + c;
        *(float4*)&Qs[r][c] = *(const float4*)src;
    }
    if (t < 16) { m_s[t] = -1e30f; l_s[t] = 0.f; }
    float ctx[4] = {0.f, 0.f, 0.f, 0.f};
    const float* biasRow = biasT + h * NB_DELTA;
    int sq_base = qt * 16;
    __syncthreads();

    for (int kt = 0; kt < S_LEN; kt += 64) {
        // stage K,V tiles (64 x 64 each)
        for (int s = 0; s < 4; s++) {
            int g = t + s * 256;
            int r = g >> 4, c = (g & 15) * 4;
            const float* base = qkv + ((size_t)(b * S_LEN + kt + r)) * 3072 + h * 64 + c;
            *(float4*)&Ks[r][c] = *(const float4*)(base + 1024);
            *(float4*)&Vs[r][c] = *(const float4*)(base + 2048);
        }
        __syncthreads();
        // scores: this thread owns key j = d, rows q = qg + 4i
        float sc[4];
        for (int i = 0; i < 4; i++) {
            int q = qg + 4 * i;
            float acc = 0.f;
            for (int kk = 0; kk < 64; kk += 4) {
                float4 qv = *(const float4*)&Qs[q][kk];
                float4 kv = *(const float4*)&Ks[d][kk];
                acc += qv.x * kv.x + qv.y * kv.y + qv.z * kv.z + qv.w * kv.w;
            }
            acc += biasRow[(kt + d) - (sq_base + q) + (S_LEN - 1)];
            sc[i] = acc;
            P[q][d] = acc;
        }
        __syncthreads();
        if (t < 64) {   // row max partials
            int r = t >> 2, seg = t & 3;
            float mx = -1e30f;
            for (int j = seg * 16; j < seg * 16 + 16; j++) mx = fmaxf(mx, P[r][j]);
            part[r][seg] = mx;
        }
        __syncthreads();
        if (t < 16) {
            float mx = fmaxf(fmaxf(part[t][0], part[t][1]), fmaxf(part[t][2], part[t][3]));
            mnew_s[t] = fmaxf(m_s[t], mx);
        }
        __syncthreads();
        for (int i = 0; i < 4; i++) {
            int q = qg + 4 * i;
            P[q][d] = __expf(sc[i] - mnew_s[q]);
        }
        __syncthreads();
        if (t < 64) {   // row sum partials
            int r = t >> 2, seg = t & 3;
            float sm = 0.f;
            for (int j = seg * 16; j < seg * 16 + 16; j++) sm += P[r][j];
            part[r][seg] = sm;
        }
        __syncthreads();
        if (t < 16) {
            float rs = part[t][0] + part[t][1] + part[t][2] + part[t][3];
            float alpha = __expf(m_s[t] - mnew_s[t]);
            l_s[t] = l_s[t] * alpha + rs;
            al_s[t] = alpha;
            m_s[t] = mnew_s[t];
        }
        __syncthreads();
        // ctx update: thread owns (q = qg+4i, dim = d)
        for (int i = 0; i < 4; i++) {
            int q = qg + 4 * i;
            float accv = 0.f;
            for (int j = 0; j < 64; j++)
                accv += P[q][j] * Vs[j][d];
            ctx[i] = ctx[i] * al_s[q] + accv;
        }
        __syncthreads();
    }
    for (int i = 0; i < 4; i++) {
        int q = qg + 4 * i;
        float o = ctx[i] / l_s[q];
        ctx_bf16[((size_t)(b * S_LEN + sq_base + q)) * 1024 + h * 64 + d] = f2bf(o);
    }
}

extern "C" void kernel_launch(void* const* d_in, const int* in_sizes, int n_in,
                              void* d_out, int out_size, void* d_ws, size_t ws_size,
                              hipStream_t stream) {
    const float* hs       = (const float*)d_in[0];
    const float* Wq       = (const float*)d_in[1];
    const float* Wk       = (const float*)d_in[2];
    const float* Wv       = (const float*)d_in[3];
    const float* Wo       = (const float*)d_in[4];
    const float* rel_bias = (const float*)d_in[5];
    float* out = (float*)d_out;

    char* ws = (char*)d_ws;
    float* biasT          = (float*)ws;           ws += 262144;      // 16*4095*4 rounded
    unsigned short* hsb   = (unsigned short*)ws;  ws += 8388608;     // 4096x1024 bf16
    unsigned short* WTqkv = (unsigned short*)ws;  ws += 6291456;     // 3072x1024 bf16
    unsigned short* WoT   = (unsigned short*)ws;  ws += 2097152;     // 1024x1024 bf16
    float* qkv            = (float*)ws;           ws += 50331648;    // 4096x3072 f32
    unsigned short* ctxb  = (unsigned short*)ws;                     // 4096x1024 bf16

    bias_table_kernel<<<(NB_DELTA + 255) / 256, 256, 0, stream>>>(rel_bias, biasT);
    cast_bf16_kernel<<<4096, 256, 0, stream>>>(hs, hsb, 4194304);
    transpose_cast_kernel<<<dim3(32, 32), 256, 0, stream>>>(Wq, WTqkv);
    transpose_cast_kernel<<<dim3(32, 32), 256, 0, stream>>>(Wk, WTqkv + 1024 * 1024);
    transpose_cast_kernel<<<dim3(32, 32), 256, 0, stream>>>(Wv, WTqkv + 2 * 1024 * 1024);
    transpose_cast_kernel<<<dim3(32, 32), 256, 0, stream>>>(Wo, WoT);

    // QKV fused: C[4096][3072]
    gemm_bt_kernel<<<dim3(24, 32), 256, 0, stream>>>(hsb, WTqkv, qkv, 1024, 3072);
    // attention
    flash_kernel<<<dim3(S_LEN / 16, NH, 2), 256, 0, stream>>>(qkv, biasT, ctxb);
    // output projection: out[4096][1024]
    gemm_bt_kernel<<<dim3(8, 32), 256, 0, stream>>>(ctxb, WoT, out, 1024, 1024);
}

// Round 2
// 337.218 us; speedup vs baseline: 8.0856x; 8.0856x over previous
//
#include <hip/hip_runtime.h>
#include <stdint.h>

#define S_LEN 2048
#define NH 16
#define NB_DELTA (2*S_LEN-1)   // 4095
#define FST 72                 // flash LDS row stride in bf16 elems (144B, 16B-aligned)

typedef __attribute__((ext_vector_type(8))) __bf16 bf16x8;
typedef __attribute__((ext_vector_type(4))) float f32x4;

__device__ __forceinline__ unsigned short f2bf(float f){
    union { float f; unsigned int u; } v; v.f = f;
    unsigned int u = v.u;
    return (unsigned short)((u + 0x7FFFu + ((u >> 16) & 1u)) >> 16);
}

// ---------------- bias table: biasT[h][delta+2047] = rel_bias[bucket(delta)][h]
__global__ __launch_bounds__(256) void bias_table_kernel(const float* __restrict__ rel_bias,
                                                         float* __restrict__ biasT){
    int t = blockIdx.x * blockDim.x + threadIdx.x;
    if (t >= NB_DELTA) return;
    int delta = t - (S_LEN - 1);          // j - i
    int bucket = (delta > 0) ? 16 : 0;
    int a = delta < 0 ? -delta : delta;
    int b;
    if (a < 8) b = a;
    else {
        int bl = 33 - __builtin_clz(a * a);   // 8 + floor(2*log2(a/8)), exact
        b = bl < 15 ? bl : 15;
    }
    bucket += b;
    for (int h = 0; h < NH; h++)
        biasT[h * NB_DELTA + t] = rel_bias[bucket * NH + h];
}

// ---------------- fp32 -> bf16 cast
__global__ __launch_bounds__(256) void cast_bf16_kernel(const float* __restrict__ in,
                                                        unsigned short* __restrict__ out, int n){
    int i = (blockIdx.x * blockDim.x + threadIdx.x) * 4;
    if (i >= n) return;
    float4 f = *(const float4*)(in + i);
    ushort4 o;
    o.x = f2bf(f.x); o.y = f2bf(f.y); o.z = f2bf(f.z); o.w = f2bf(f.w);
    *(ushort4*)(out + i) = o;
}

// ---------------- transpose + cast: dst[n][1024] = bf16(src[k][n]), 1024x1024
__global__ __launch_bounds__(256) void transpose_cast_kernel(const float* __restrict__ src,
                                                             unsigned short* __restrict__ dst){
    __shared__ float tile[32][33];
    int bx = blockIdx.x, by = blockIdx.y;
    int tx = threadIdx.x & 31, ty = threadIdx.x >> 5;   // ty 0..7
    for (int i = 0; i < 4; i++)
        tile[ty + 8*i][tx] = src[(size_t)(by*32 + ty + 8*i) * 1024 + bx*32 + tx];
    __syncthreads();
    for (int i = 0; i < 4; i++)
        dst[(size_t)(bx*32 + ty + 8*i) * 1024 + by*32 + tx] = f2bf(tile[tx][ty + 8*i]);
}

// ---------------- bf16 MFMA GEMM: C[m][n] = sum_k A[m][k] * BT[n][k]
// BM=BN=128, BK=32, 256 threads (4 waves, 2x2 of 64x64)
// MODE 0: fp32 row-major out; MODE 1: bf16 row-major out;
// MODE 2: bf16 transposed out per batch: Vt[b*1024 + n][2048] (n in 0..1023, token s = m & 2047)
#define GLDS 40
template<int MODE>
__global__ __launch_bounds__(256) void gemm_bt_kernel(const unsigned short* __restrict__ A,
                                                      const unsigned short* __restrict__ BT,
                                                      void* __restrict__ Cout,
                                                      int Kdim, int ldc){
    __shared__ __align__(16) unsigned short As[128 * GLDS];
    __shared__ __align__(16) unsigned short Bs[128 * GLDS];
    int t = threadIdx.x;
    int wave = t >> 6, lane = t & 63;
    int quad = lane >> 4, l16 = lane & 15;
    int wm = (wave >> 1) * 64, wn = (wave & 1) * 64;
    size_t row0 = (size_t)blockIdx.y * 128, col0 = (size_t)blockIdx.x * 128;

    f32x4 acc[4][4] = {};

    for (int kt = 0; kt < Kdim; kt += 32) {
        for (int s = 0; s < 2; s++) {
            int g = t + s * 256;           // 512 granules of 8 bf16
            int r = g >> 2, kg = (g & 3) * 8;
            *(int4*)(&As[r * GLDS + kg]) = *(const int4*)(A + (row0 + r) * Kdim + kt + kg);
            *(int4*)(&Bs[r * GLDS + kg]) = *(const int4*)(BT + (col0 + r) * Kdim + kt + kg);
        }
        __syncthreads();
        bf16x8 a[4], b[4];
        for (int i = 0; i < 4; i++)
            a[i] = *(const bf16x8*)(&As[(wm + i*16 + l16) * GLDS + quad * 8]);
        for (int j = 0; j < 4; j++)
            b[j] = *(const bf16x8*)(&Bs[(wn + j*16 + l16) * GLDS + quad * 8]);
        for (int i = 0; i < 4; i++)
            for (int j = 0; j < 4; j++)
                acc[i][j] = __builtin_amdgcn_mfma_f32_16x16x32_bf16(a[i], b[j], acc[i][j], 0, 0, 0);
        __syncthreads();
    }
    // C/D layout: col = lane&15, row = quad*4 + reg
    for (int i = 0; i < 4; i++)
        for (int j = 0; j < 4; j++) {
            size_t r0 = row0 + wm + i*16 + quad*4;
            size_t c  = col0 + wn + j*16 + l16;
            if (MODE == 0) {
                float* C = (float*)Cout;
                for (int r = 0; r < 4; r++)
                    C[(r0 + r) * ldc + c] = acc[i][j][r];
            } else if (MODE == 1) {
                unsigned short* C = (unsigned short*)Cout;
                for (int r = 0; r < 4; r++)
                    C[(r0 + r) * ldc + c] = f2bf(acc[i][j][r]);
            } else {
                unsigned short* C = (unsigned short*)Cout;
                int bb = (int)(r0 >> 11);
                int s  = (int)(r0 & 2047);
                ushort4 pk;
                pk.x = f2bf(acc[i][j][0]); pk.y = f2bf(acc[i][j][1]);
                pk.z = f2bf(acc[i][j][2]); pk.w = f2bf(acc[i][j][3]);
                *(ushort4*)(C + ((size_t)(bb * 1024) + c) * 2048 + s) = pk;
            }
        }
}

// ---------------- MFMA flash attention
// grid (S/64, NH, B), 256 threads = 4 waves, 16 q-rows per wave, 64-key tiles.
// qk: [B*S][2048] bf16, cols 0..1023 = Q (h*64+d), 1024..2047 = K.
// vt: [B*1024][S] bf16, row = b*1024 + h*64 + d  (V transposed)
__global__ __launch_bounds__(256, 4) void flash2_kernel(
    const unsigned short* __restrict__ qk,
    const unsigned short* __restrict__ vt,
    const float* __restrict__ biasT,
    unsigned short* __restrict__ ctxb)
{
    const int qt = blockIdx.x, h = blockIdx.y, b = blockIdx.z;
    const int t = threadIdx.x;
    const int w = t >> 6, lane = t & 63, quad = lane >> 4, l16 = lane & 15;
    const int q0 = qt * 64;
    const int wq0 = q0 + w * 16;

    __shared__ __align__(16) unsigned short Qs[64 * FST];
    __shared__ __align__(16) unsigned short Ks[64 * FST];
    __shared__ __align__(16) unsigned short Vts[64 * FST];
    __shared__ __align__(16) unsigned short Ps[4 * 16 * FST];

    // stage Q tile (64 x 64 bf16), coalesced int4
    {
        int r0 = t >> 3, c0 = (t & 7) * 8;
        int g1 = t + 256;
        int r1 = g1 >> 3, c1 = (g1 & 7) * 8;
        const unsigned short* base = qk + (size_t)(b * S_LEN + q0) * 2048 + h * 64;
        *(int4*)&Qs[r0 * FST + c0] = *(const int4*)(base + (size_t)r0 * 2048 + c0);
        *(int4*)&Qs[r1 * FST + c1] = *(const int4*)(base + (size_t)r1 * 2048 + c1);
    }
    __syncthreads();
    bf16x8 qa[2];
    qa[0] = *(const bf16x8*)&Qs[(w * 16 + l16) * FST + quad * 8];
    qa[1] = *(const bf16x8*)&Qs[(w * 16 + l16) * FST + 32 + quad * 8];

    float m_run[4], l_run[4];
    for (int r = 0; r < 4; r++) { m_run[r] = -1e30f; l_run[r] = 0.f; }
    f32x4 ctx[4] = {};

    const float* biasRow = biasT + h * NB_DELTA + 2047;

    for (int kt = 0; kt < S_LEN; kt += 64) {
        __syncthreads();   // previous tile fully consumed
        {
            int r0 = t >> 3, c0 = (t & 7) * 8;
            int g1 = t + 256;
            int r1 = g1 >> 3, c1 = (g1 & 7) * 8;
            const unsigned short* kbase = qk + (size_t)(b * S_LEN + kt) * 2048 + 1024 + h * 64;
            *(int4*)&Ks[r0 * FST + c0] = *(const int4*)(kbase + (size_t)r0 * 2048 + c0);
            *(int4*)&Ks[r1 * FST + c1] = *(const int4*)(kbase + (size_t)r1 * 2048 + c1);
            const unsigned short* vbase = vt + (size_t)(b * 1024 + h * 64) * 2048 + kt;
            *(int4*)&Vts[r0 * FST + c0] = *(const int4*)(vbase + (size_t)r0 * 2048 + c0);
            *(int4*)&Vts[r1 * FST + c1] = *(const int4*)(vbase + (size_t)r1 * 2048 + c1);
        }
        __syncthreads();

        // S = Q K^T  (rows m=q via quad*4+reg, cols n=key via l16+16*nb)
        f32x4 accs[4] = {};
        for (int ks = 0; ks < 2; ks++)
            for (int nb = 0; nb < 4; nb++) {
                bf16x8 kb = *(const bf16x8*)&Ks[(nb * 16 + l16) * FST + ks * 32 + quad * 8];
                accs[nb] = __builtin_amdgcn_mfma_f32_16x16x32_bf16(qa[ks], kb, accs[nb], 0, 0, 0);
            }

        // bias + online softmax (stats lane-local per row r)
        float p[4][4], tmax[4];
        int dbase = kt + l16 - wq0 - quad * 4;
        for (int r = 0; r < 4; r++) tmax[r] = -1e30f;
        for (int nb = 0; nb < 4; nb++)
            for (int r = 0; r < 4; r++) {
                float sv = accs[nb][r] + biasRow[dbase + nb * 16 - r];
                p[nb][r] = sv;
                tmax[r] = fmaxf(tmax[r], sv);
            }
        float alpha[4];
        for (int r = 0; r < 4; r++) {
            float tm = tmax[r];
            tm = fmaxf(tm, __shfl_xor(tm, 1, 64));
            tm = fmaxf(tm, __shfl_xor(tm, 2, 64));
            tm = fmaxf(tm, __shfl_xor(tm, 4, 64));
            tm = fmaxf(tm, __shfl_xor(tm, 8, 64));
            float mn = fmaxf(m_run[r], tm);
            alpha[r] = __expf(m_run[r] - mn);
            m_run[r] = mn;
        }
        float rsum[4] = {0.f, 0.f, 0.f, 0.f};
        for (int nb = 0; nb < 4; nb++)
            for (int r = 0; r < 4; r++) {
                float pv = __expf(p[nb][r] - m_run[r]);
                p[nb][r] = pv;
                rsum[r] += pv;
            }
        for (int r = 0; r < 4; r++) {
            float rs = rsum[r];
            rs += __shfl_xor(rs, 1, 64);
            rs += __shfl_xor(rs, 2, 64);
            rs += __shfl_xor(rs, 4, 64);
            rs += __shfl_xor(rs, 8, 64);
            l_run[r] = l_run[r] * alpha[r] + rs;
        }
        // P (C-layout) -> LDS, wave-private buffer, no block barrier needed
        for (int nb = 0; nb < 4; nb++)
            for (int r = 0; r < 4; r++)
                Ps[(w * 16 + quad * 4 + r) * FST + nb * 16 + l16] = f2bf(p[nb][r]);
        // rescale ctx
        for (int nd = 0; nd < 4; nd++)
            for (int r = 0; r < 4; r++)
                ctx[nd][r] *= alpha[r];
        // ctx += P V  (A-frag = Ps rows, B-frag = Vt rows)
        for (int ks = 0; ks < 2; ks++) {
            bf16x8 pa = *(const bf16x8*)&Ps[(w * 16 + l16) * FST + ks * 32 + quad * 8];
            for (int nd = 0; nd < 4; nd++) {
                bf16x8 vb = *(const bf16x8*)&Vts[(nd * 16 + l16) * FST + ks * 32 + quad * 8];
                ctx[nd] = __builtin_amdgcn_mfma_f32_16x16x32_bf16(pa, vb, ctx[nd], 0, 0, 0);
            }
        }
    }
    // epilogue: rows q = wq0 + quad*4 + r, cols d = nd*16 + l16
    for (int r = 0; r < 4; r++) {
        float inv = 1.f / l_run[r];
        size_t row = (size_t)(b * S_LEN + wq0 + quad * 4 + r);
        for (int nd = 0; nd < 4; nd++)
            ctxb[row * 1024 + h * 64 + nd * 16 + l16] = f2bf(ctx[nd][r] * inv);
    }
}

extern "C" void kernel_launch(void* const* d_in, const int* in_sizes, int n_in,
                              void* d_out, int out_size, void* d_ws, size_t ws_size,
                              hipStream_t stream) {
    const float* hs       = (const float*)d_in[0];
    const float* Wq       = (const float*)d_in[1];
    const float* Wk       = (const float*)d_in[2];
    const float* Wv       = (const float*)d_in[3];
    const float* Wo       = (const float*)d_in[4];
    const float* rel_bias = (const float*)d_in[5];
    float* out = (float*)d_out;

    char* ws = (char*)d_ws;
    float* biasT          = (float*)ws;           ws += 262144;      // 16*4095*4
    unsigned short* hsb   = (unsigned short*)ws;  ws += 8388608;     // 4096x1024 bf16
    unsigned short* WTqk  = (unsigned short*)ws;  ws += 4194304;     // 2048x1024 bf16
    unsigned short* WTv   = (unsigned short*)ws;  ws += 2097152;     // 1024x1024 bf16
    unsigned short* WoT   = (unsigned short*)ws;  ws += 2097152;     // 1024x1024 bf16
    unsigned short* qkbuf = (unsigned short*)ws;  ws += 16777216;    // 4096x2048 bf16
    unsigned short* Vtg   = (unsigned short*)ws;  ws += 8388608;     // 2048x2048 bf16
    unsigned short* ctxb  = (unsigned short*)ws;                     // 4096x1024 bf16

    bias_table_kernel<<<(NB_DELTA + 255) / 256, 256, 0, stream>>>(rel_bias, biasT);
    cast_bf16_kernel<<<4096, 256, 0, stream>>>(hs, hsb, 4194304);
    transpose_cast_kernel<<<dim3(32, 32), 256, 0, stream>>>(Wq, WTqk);
    transpose_cast_kernel<<<dim3(32, 32), 256, 0, stream>>>(Wk, WTqk + 1024 * 1024);
    transpose_cast_kernel<<<dim3(32, 32), 256, 0, stream>>>(Wv, WTv);
    transpose_cast_kernel<<<dim3(32, 32), 256, 0, stream>>>(Wo, WoT);

    // Q|K projection -> bf16 row-major [4096][2048]
    gemm_bt_kernel<1><<<dim3(16, 32), 256, 0, stream>>>(hsb, WTqk, qkbuf, 1024, 2048);
    // V projection -> bf16 transposed [b*1024 + dim][2048 tokens]
    gemm_bt_kernel<2><<<dim3(8, 32), 256, 0, stream>>>(hsb, WTv, Vtg, 1024, 0);
    // attention
    flash2_kernel<<<dim3(S_LEN / 64, NH, 2), 256, 0, stream>>>(qkbuf, Vtg, biasT, ctxb);
    // output projection -> fp32
    gemm_bt_kernel<0><<<dim3(8, 32), 256, 0, stream>>>(ctxb, WoT, out, 1024, 1024);
}

// Round 3
// 249.638 us; speedup vs baseline: 10.9222x; 1.3508x over previous
//
#include <hip/hip_runtime.h>
#include <stdint.h>

#define S_LEN 2048
#define NH 16
#define NB_DELTA (2*S_LEN-1)   // 4095
#define FST 72                 // flash LDS row stride in bf16 elems

typedef __attribute__((ext_vector_type(8))) __bf16 bf16x8;
typedef __attribute__((ext_vector_type(4))) float f32x4;

__device__ __forceinline__ unsigned short f2bf(float f){   // RNE
    union { float f; unsigned int u; } v; v.f = f;
    unsigned int u = v.u;
    return (unsigned short)((u + 0x7FFFu + ((u >> 16) & 1u)) >> 16);
}
__device__ __forceinline__ unsigned short f2bf_fast(float f){   // round-half-up
    union { float f; unsigned int u; } v; v.f = f;
    return (unsigned short)((v.u + 0x8000u) >> 16);
}

// ---------------- bias table: biasT[h][delta+2047] = rel_bias[bucket(delta)][h]
__global__ __launch_bounds__(256) void bias_table_kernel(const float* __restrict__ rel_bias,
                                                         float* __restrict__ biasT){
    int t = blockIdx.x * blockDim.x + threadIdx.x;
    if (t >= NB_DELTA) return;
    int delta = t - (S_LEN - 1);          // j - i
    int bucket = (delta > 0) ? 16 : 0;
    int a = delta < 0 ? -delta : delta;
    int b;
    if (a < 8) b = a;
    else {
        int bl = 33 - __builtin_clz(a * a);   // 8 + floor(2*log2(a/8)), exact
        b = bl < 15 ? bl : 15;
    }
    bucket += b;
    for (int h = 0; h < NH; h++)
        biasT[h * NB_DELTA + t] = rel_bias[bucket * NH + h];
}

// ---------------- fp32 -> bf16 cast
__global__ __launch_bounds__(256) void cast_bf16_kernel(const float* __restrict__ in,
                                                        unsigned short* __restrict__ out, int n){
    int i = (blockIdx.x * blockDim.x + threadIdx.x) * 4;
    if (i >= n) return;
    float4 f = *(const float4*)(in + i);
    ushort4 o;
    o.x = f2bf(f.x); o.y = f2bf(f.y); o.z = f2bf(f.z); o.w = f2bf(f.w);
    *(ushort4*)(out + i) = o;
}

// ---------------- fused transpose+cast of the 4 weight matrices (1024x1024 each)
__global__ __launch_bounds__(256) void transpose_cast4_kernel(
    const float* __restrict__ W0, const float* __restrict__ W1,
    const float* __restrict__ W2, const float* __restrict__ W3,
    unsigned short* __restrict__ D0, unsigned short* __restrict__ D1,
    unsigned short* __restrict__ D2, unsigned short* __restrict__ D3){
    const float* src; unsigned short* dst;
    switch (blockIdx.z) {
        case 0: src = W0; dst = D0; break;
        case 1: src = W1; dst = D1; break;
        case 2: src = W2; dst = D2; break;
        default: src = W3; dst = D3; break;
    }
    __shared__ float tile[32][33];
    int bx = blockIdx.x, by = blockIdx.y;
    int tx = threadIdx.x & 31, ty = threadIdx.x >> 5;
    for (int i = 0; i < 4; i++)
        tile[ty + 8*i][tx] = src[(size_t)(by*32 + ty + 8*i) * 1024 + bx*32 + tx];
    __syncthreads();
    for (int i = 0; i < 4; i++)
        dst[(size_t)(bx*32 + ty + 8*i) * 1024 + by*32 + tx] = f2bf(tile[tx][ty + 8*i]);
}

// ---------------- bf16 MFMA GEMM: C[m][n] = sum_k A[m][k] * BT[n][k]
// MODE 0: fp32 out; MODE 1: bf16 out; MODE 2: bf16 transposed out Vt[b*1024+n][2048]
#define GLDS 40
template<int MODE>
__global__ __launch_bounds__(256) void gemm_bt_kernel(const unsigned short* __restrict__ A,
                                                      const unsigned short* __restrict__ BT,
                                                      void* __restrict__ Cout,
                                                      int Kdim, int ldc){
    __shared__ __align__(16) unsigned short As[128 * GLDS];
    __shared__ __align__(16) unsigned short Bs[128 * GLDS];
    int t = threadIdx.x;
    int wave = t >> 6, lane = t & 63;
    int quad = lane >> 4, l16 = lane & 15;
    int wm = (wave >> 1) * 64, wn = (wave & 1) * 64;
    size_t row0 = (size_t)blockIdx.y * 128, col0 = (size_t)blockIdx.x * 128;

    f32x4 acc[4][4] = {};

    for (int kt = 0; kt < Kdim; kt += 32) {
        for (int s = 0; s < 2; s++) {
            int g = t + s * 256;
            int r = g >> 2, kg = (g & 3) * 8;
            *(int4*)(&As[r * GLDS + kg]) = *(const int4*)(A + (row0 + r) * Kdim + kt + kg);
            *(int4*)(&Bs[r * GLDS + kg]) = *(const int4*)(BT + (col0 + r) * Kdim + kt + kg);
        }
        __syncthreads();
        bf16x8 a[4], b[4];
        for (int i = 0; i < 4; i++)
            a[i] = *(const bf16x8*)(&As[(wm + i*16 + l16) * GLDS + quad * 8]);
        for (int j = 0; j < 4; j++)
            b[j] = *(const bf16x8*)(&Bs[(wn + j*16 + l16) * GLDS + quad * 8]);
        for (int i = 0; i < 4; i++)
            for (int j = 0; j < 4; j++)
                acc[i][j] = __builtin_amdgcn_mfma_f32_16x16x32_bf16(a[i], b[j], acc[i][j], 0, 0, 0);
        __syncthreads();
    }
    for (int i = 0; i < 4; i++)
        for (int j = 0; j < 4; j++) {
            size_t r0 = row0 + wm + i*16 + quad*4;
            size_t c  = col0 + wn + j*16 + l16;
            if (MODE == 0) {
                float* C = (float*)Cout;
                for (int r = 0; r < 4; r++)
                    C[(r0 + r) * ldc + c] = acc[i][j][r];
            } else if (MODE == 1) {
                unsigned short* C = (unsigned short*)Cout;
                for (int r = 0; r < 4; r++)
                    C[(r0 + r) * ldc + c] = f2bf(acc[i][j][r]);
            } else {
                unsigned short* C = (unsigned short*)Cout;
                int bb = (int)(r0 >> 11);
                int s  = (int)(r0 & 2047);
                ushort4 pk;
                pk.x = f2bf(acc[i][j][0]); pk.y = f2bf(acc[i][j][1]);
                pk.z = f2bf(acc[i][j][2]); pk.w = f2bf(acc[i][j][3]);
                *(ushort4*)(C + ((size_t)(bb * 1024) + c) * 2048 + s) = pk;
            }
        }
}

// ---------------- MFMA flash attention, S^T formulation, no-max softmax.
// grid (S/64, NH, B), 256 threads = 4 waves; wave w owns q = q0 + w*16 + l16.
// qk: [B*S][2048] bf16 (Q | K); vt: [B*1024][2048] bf16 (V transposed).
// S^T = K·Q^T: C-layout col = q (lane&15)  => softmax stats are lane-local scalars.
// exp shift: bias table pre-shifted by -16 (exp(s-16), divides out in the final 1/l).
__global__ __launch_bounds__(256, 4) void flash3_kernel(
    const unsigned short* __restrict__ qk,
    const unsigned short* __restrict__ vt,
    const float* __restrict__ biasT,
    unsigned short* __restrict__ ctxb)
{
    const int qt = blockIdx.x, h = blockIdx.y, b = blockIdx.z;
    const int t = threadIdx.x;
    const int w = t >> 6, lane = t & 63, quad = lane >> 4, l16 = lane & 15;
    const int q0 = qt * 64;

    __shared__ __align__(16) unsigned short Qs[64 * FST];
    __shared__ __align__(16) unsigned short Ks[64 * FST];
    __shared__ __align__(16) unsigned short Vts[64 * FST];
    __shared__ __align__(16) unsigned short Pb[64 * FST];
    __shared__ float bias_s[128];

    // stage Q tile (64 x 64 bf16)
    {
        int r0 = t >> 3, c0 = (t & 7) * 8;
        int g1 = t + 256;
        int r1 = g1 >> 3, c1 = (g1 & 7) * 8;
        const unsigned short* base = qk + (size_t)(b * S_LEN + q0) * 2048 + h * 64;
        *(int4*)&Qs[r0 * FST + c0] = *(const int4*)(base + (size_t)r0 * 2048 + c0);
        *(int4*)&Qs[r1 * FST + c1] = *(const int4*)(base + (size_t)r1 * 2048 + c1);
    }
    __syncthreads();
    // Q as B-operand: [n = q = l16][k = quad*8 + :8]
    bf16x8 qb[2];
    qb[0] = *(const bf16x8*)&Qs[(w * 16 + l16) * FST + quad * 8];
    qb[1] = *(const bf16x8*)&Qs[(w * 16 + l16) * FST + 32 + quad * 8];

    float rsum = 0.f;
    f32x4 ctx[4] = {};   // ctx^T: [d = nd*16 + quad*4 + r][q = l16]

    const float* biasRow = biasT + h * NB_DELTA + 2047;

    for (int kt = 0; kt < S_LEN; kt += 64) {
        __syncthreads();
        {
            int r0 = t >> 3, c0 = (t & 7) * 8;
            int g1 = t + 256;
            int r1 = g1 >> 3, c1 = (g1 & 7) * 8;
            const unsigned short* kbase = qk + (size_t)(b * S_LEN + kt) * 2048 + 1024 + h * 64;
            *(int4*)&Ks[r0 * FST + c0] = *(const int4*)(kbase + (size_t)r0 * 2048 + c0);
            *(int4*)&Ks[r1 * FST + c1] = *(const int4*)(kbase + (size_t)r1 * 2048 + c1);
            const unsigned short* vbase = vt + (size_t)(b * 1024 + h * 64) * 2048 + kt;
            *(int4*)&Vts[r0 * FST + c0] = *(const int4*)(vbase + (size_t)r0 * 2048 + c0);
            *(int4*)&Vts[r1 * FST + c1] = *(const int4*)(vbase + (size_t)r1 * 2048 + c1);
            if (t < 128) bias_s[t] = biasRow[kt - q0 - 63 + t] - 16.0f;  // exp shift folded in
        }
        __syncthreads();

        // S^T = K Q^T : A = K rows (m=j), B = Q rows (n=q)
        f32x4 st[4] = {};
        for (int ks = 0; ks < 2; ks++)
            for (int nb = 0; nb < 4; nb++) {
                bf16x8 ka = *(const bf16x8*)&Ks[(nb * 16 + l16) * FST + ks * 32 + quad * 8];
                st[nb] = __builtin_amdgcn_mfma_f32_16x16x32_bf16(ka, qb[ks], st[nb], 0, 0, 0);
            }
        // st[nb][r]: j = kt + nb*16 + quad*4 + r,  q = q0 + w*16 + l16 (lane-fixed)
        int ib = quad * 4 - w * 16 - l16 + 63;
        for (int nb = 0; nb < 4; nb++) {
            float e0 = __expf(st[nb][0] + bias_s[ib + nb * 16 + 0]);
            float e1 = __expf(st[nb][1] + bias_s[ib + nb * 16 + 1]);
            float e2 = __expf(st[nb][2] + bias_s[ib + nb * 16 + 2]);
            float e3 = __expf(st[nb][3] + bias_s[ib + nb * 16 + 3]);
            rsum += (e0 + e1) + (e2 + e3);
            ushort4 pk;
            pk.x = f2bf_fast(e0); pk.y = f2bf_fast(e1);
            pk.z = f2bf_fast(e2); pk.w = f2bf_fast(e3);
            // P^T rows = q (wave-private 16 rows), cols = j-local; 4 consecutive j -> b64
            *(ushort4*)&Pb[(w * 16 + l16) * FST + nb * 16 + quad * 4] = pk;
        }
        // ctx^T += Vt · P^T : A = Vt rows (m=d), B = P^T rows (n=q); k = j
        for (int ks = 0; ks < 2; ks++) {
            bf16x8 pb = *(const bf16x8*)&Pb[(w * 16 + l16) * FST + ks * 32 + quad * 8];
            for (int nd = 0; nd < 4; nd++) {
                bf16x8 va = *(const bf16x8*)&Vts[(nd * 16 + l16) * FST + ks * 32 + quad * 8];
                ctx[nd] = __builtin_amdgcn_mfma_f32_16x16x32_bf16(va, pb, ctx[nd], 0, 0, 0);
            }
        }
    }
    // epilogue: l = sum over quads; write ctx[q][d], 4 d-consecutive per store
    float rs = rsum;
    rs += __shfl_xor(rs, 16, 64);
    rs += __shfl_xor(rs, 32, 64);
    float inv = 1.f / rs;
    size_t row = (size_t)(b * S_LEN + q0 + w * 16 + l16);
    for (int nd = 0; nd < 4; nd++) {
        ushort4 pk;
        pk.x = f2bf(ctx[nd][0] * inv); pk.y = f2bf(ctx[nd][1] * inv);
        pk.z = f2bf(ctx[nd][2] * inv); pk.w = f2bf(ctx[nd][3] * inv);
        *(ushort4*)&ctxb[row * 1024 + h * 64 + nd * 16 + quad * 4] = pk;
    }
}

extern "C" void kernel_launch(void* const* d_in, const int* in_sizes, int n_in,
                              void* d_out, int out_size, void* d_ws, size_t ws_size,
                              hipStream_t stream) {
    const float* hs       = (const float*)d_in[0];
    const float* Wq       = (const float*)d_in[1];
    const float* Wk       = (const float*)d_in[2];
    const float* Wv       = (const float*)d_in[3];
    const float* Wo       = (const float*)d_in[4];
    const float* rel_bias = (const float*)d_in[5];
    float* out = (float*)d_out;

    char* ws = (char*)d_ws;
    float* biasT          = (float*)ws;           ws += 262144;      // 16*4095*4 (+pad)
    unsigned short* hsb   = (unsigned short*)ws;  ws += 8388608;     // 4096x1024 bf16
    unsigned short* WTqk  = (unsigned short*)ws;  ws += 4194304;     // 2048x1024 bf16
    unsigned short* WTv   = (unsigned short*)ws;  ws += 2097152;     // 1024x1024 bf16
    unsigned short* WoT   = (unsigned short*)ws;  ws += 2097152;     // 1024x1024 bf16
    unsigned short* qkbuf = (unsigned short*)ws;  ws += 16777216;    // 4096x2048 bf16
    unsigned short* Vtg   = (unsigned short*)ws;  ws += 8388608;     // 2048x2048 bf16
    unsigned short* ctxb  = (unsigned short*)ws;                     // 4096x1024 bf16

    bias_table_kernel<<<(NB_DELTA + 255) / 256, 256, 0, stream>>>(rel_bias, biasT);
    cast_bf16_kernel<<<4096, 256, 0, stream>>>(hs, hsb, 4194304);
    transpose_cast4_kernel<<<dim3(32, 32, 4), 256, 0, stream>>>(
        Wq, Wk, Wv, Wo, WTqk, WTqk + 1024 * 1024, WTv, WoT);

    // Q|K projection -> bf16 row-major [4096][2048]
    gemm_bt_kernel<1><<<dim3(16, 32), 256, 0, stream>>>(hsb, WTqk, qkbuf, 1024, 2048);
    // V projection -> bf16 transposed [b*1024 + dim][2048 tokens]
    gemm_bt_kernel<2><<<dim3(8, 32), 256, 0, stream>>>(hsb, WTv, Vtg, 1024, 0);
    // attention
    flash3_kernel<<<dim3(S_LEN / 64, NH, 2), 256, 0, stream>>>(qkbuf, Vtg, biasT, ctxb);
    // output projection -> fp32
    gemm_bt_kernel<0><<<dim3(8, 32), 256, 0, stream>>>(ctxb, WoT, out, 1024, 1024);
}

// Round 4
// 225.970 us; speedup vs baseline: 12.0663x; 1.1047x over previous
//
#include <hip/hip_runtime.h>
#include <stdint.h>

#define S_LEN 2048
#define NH 16
#define NB_DELTA (2*S_LEN-1)   // 4095
#define FST 72                 // flash LDS row stride in bf16 elems

typedef __attribute__((ext_vector_type(8))) __bf16 bf16x8;
typedef __attribute__((ext_vector_type(4))) float f32x4;

__device__ __forceinline__ unsigned short f2bf(float f){   // RNE
    union { float f; unsigned int u; } v; v.f = f;
    unsigned int u = v.u;
    return (unsigned short)((u + 0x7FFFu + ((u >> 16) & 1u)) >> 16);
}
__device__ __forceinline__ unsigned short f2bf_fast(float f){   // round-half-up
    union { float f; unsigned int u; } v; v.f = f;
    return (unsigned short)((v.u + 0x8000u) >> 16);
}

// async global->LDS, 16B per lane; LDS dest = wave-uniform base + lane*16
__device__ __forceinline__ void gload16(const void* g, void* l){
    __builtin_amdgcn_global_load_lds(
        (const __attribute__((address_space(1))) void*)(uintptr_t)g,
        (__attribute__((address_space(3))) void*)(uintptr_t)l, 16, 0, 0);
}

// ---------------- bias table: biasT[h][delta+2047] = rel_bias[bucket(delta)][h]
__global__ __launch_bounds__(256) void bias_table_kernel(const float* __restrict__ rel_bias,
                                                         float* __restrict__ biasT){
    int t = blockIdx.x * blockDim.x + threadIdx.x;
    if (t >= NB_DELTA) return;
    int delta = t - (S_LEN - 1);          // j - i
    int bucket = (delta > 0) ? 16 : 0;
    int a = delta < 0 ? -delta : delta;
    int b;
    if (a < 8) b = a;
    else {
        int bl = 33 - __builtin_clz(a * a);   // 8 + floor(2*log2(a/8)), exact
        b = bl < 15 ? bl : 15;
    }
    bucket += b;
    for (int h = 0; h < NH; h++)
        biasT[h * NB_DELTA + t] = rel_bias[bucket * NH + h];
}

// ---------------- fp32 -> bf16 cast
__global__ __launch_bounds__(256) void cast_bf16_kernel(const float* __restrict__ in,
                                                        unsigned short* __restrict__ out, int n){
    int i = (blockIdx.x * blockDim.x + threadIdx.x) * 4;
    if (i >= n) return;
    float4 f = *(const float4*)(in + i);
    ushort4 o;
    o.x = f2bf(f.x); o.y = f2bf(f.y); o.z = f2bf(f.z); o.w = f2bf(f.w);
    *(ushort4*)(out + i) = o;
}

// ---------------- fused transpose+cast of the 4 weight matrices (1024x1024 each)
__global__ __launch_bounds__(256) void transpose_cast4_kernel(
    const float* __restrict__ W0, const float* __restrict__ W1,
    const float* __restrict__ W2, const float* __restrict__ W3,
    unsigned short* __restrict__ D0, unsigned short* __restrict__ D1,
    unsigned short* __restrict__ D2, unsigned short* __restrict__ D3){
    const float* src; unsigned short* dst;
    switch (blockIdx.z) {
        case 0: src = W0; dst = D0; break;
        case 1: src = W1; dst = D1; break;
        case 2: src = W2; dst = D2; break;
        default: src = W3; dst = D3; break;
    }
    __shared__ float tile[32][33];
    int bx = blockIdx.x, by = blockIdx.y;
    int tx = threadIdx.x & 31, ty = threadIdx.x >> 5;
    for (int i = 0; i < 4; i++)
        tile[ty + 8*i][tx] = src[(size_t)(by*32 + ty + 8*i) * 1024 + bx*32 + tx];
    __syncthreads();
    for (int i = 0; i < 4; i++)
        dst[(size_t)(bx*32 + ty + 8*i) * 1024 + by*32 + tx] = f2bf(tile[tx][ty + 8*i]);
}

// ---------------- bf16 MFMA GEMM, m97-style global_load_lds staging.
// C[m][n] = sum_k A[m][k] * BT[n][k]; 128x128 tile, BK=32, unpadded 64B LDS rows.
// MODE 0: fp32 row-major into C0 (ldc).
// MODE 1: cols<2048 -> bf16 row-major into C1 (ldc=2048); cols>=2048 -> transposed
//         bf16 into C2: Vt[(batch*1024 + (c-2048))][2048 tokens].
template<int MODE>
__global__ __launch_bounds__(256) void gemm_bt_kernel(const unsigned short* __restrict__ A,
                                                      const unsigned short* __restrict__ BT,
                                                      float* __restrict__ C0,
                                                      unsigned short* __restrict__ C1,
                                                      unsigned short* __restrict__ C2,
                                                      int Kdim, int ldc){
    __shared__ __align__(16) unsigned short As[128 * 32];
    __shared__ __align__(16) unsigned short Bs[128 * 32];
    const int t = threadIdx.x;
    const int wave = t >> 6, lane = t & 63;
    const int quad = lane >> 4, l16 = lane & 15;
    const int wm = (wave >> 1) * 64, wn = (wave & 1) * 64;
    const size_t row0 = (size_t)blockIdx.y * 128, col0 = (size_t)blockIdx.x * 128;

    // per-lane global source for the async stage: lane l covers row (l>>2), col (l&3)*8
    const unsigned short* ga = A  + (row0 + wave * 32 + (lane >> 2)) * (size_t)Kdim + (lane & 3) * 8;
    const unsigned short* gb = BT + (col0 + wave * 32 + (lane >> 2)) * (size_t)Kdim + (lane & 3) * 8;
    unsigned short* la0 = &As[(wave * 32) * 32];
    unsigned short* la1 = &As[(wave * 32 + 16) * 32];
    unsigned short* lb0 = &Bs[(wave * 32) * 32];
    unsigned short* lb1 = &Bs[(wave * 32 + 16) * 32];
    const size_t rstep = (size_t)16 * Kdim;

    f32x4 acc[4][4] = {};

    for (int kt = 0; kt < Kdim; kt += 32) {
        gload16(ga + kt,         la0);
        gload16(ga + rstep + kt, la1);
        gload16(gb + kt,         lb0);
        gload16(gb + rstep + kt, lb1);
        __syncthreads();
        bf16x8 a[4], b[4];
        for (int i = 0; i < 4; i++)
            a[i] = *(const bf16x8*)(&As[(wm + i*16 + l16) * 32 + quad * 8]);
        for (int j = 0; j < 4; j++)
            b[j] = *(const bf16x8*)(&Bs[(wn + j*16 + l16) * 32 + quad * 8]);
        for (int i = 0; i < 4; i++)
            for (int j = 0; j < 4; j++)
                acc[i][j] = __builtin_amdgcn_mfma_f32_16x16x32_bf16(a[i], b[j], acc[i][j], 0, 0, 0);
        __syncthreads();
    }
    // C/D layout: col = lane&15, row = quad*4 + reg
    for (int i = 0; i < 4; i++)
        for (int j = 0; j < 4; j++) {
            size_t r0 = row0 + wm + i*16 + quad*4;
            size_t c  = col0 + wn + j*16 + l16;
            if (MODE == 0) {
                for (int r = 0; r < 4; r++)
                    C0[(r0 + r) * ldc + c] = acc[i][j][r];
            } else {
                if (c < 2048) {
                    for (int r = 0; r < 4; r++)
                        C1[(r0 + r) * 2048 + c] = f2bf(acc[i][j][r]);
                } else {
                    int bb = (int)(r0 >> 11);
                    int s  = (int)(r0 & 2047);
                    ushort4 pk;
                    pk.x = f2bf(acc[i][j][0]); pk.y = f2bf(acc[i][j][1]);
                    pk.z = f2bf(acc[i][j][2]); pk.w = f2bf(acc[i][j][3]);
                    *(ushort4*)(C2 + ((size_t)(bb * 1024) + (c - 2048)) * 2048 + s) = pk;
                }
            }
        }
}

// ---------------- MFMA flash attention, S^T formulation, no-max softmax.
// 128 q per block, 4 waves x 32 q (two 16-q n-tiles) -> every K/V frag read feeds 2 MFMAs.
// qk: [B*S][2048] bf16 (Q | K); vt: [B*1024][2048] bf16 (V transposed).
// exp shift folded into bias (exp(s-16), divides out in final 1/l).
__global__ __launch_bounds__(256, 4) void flash4_kernel(
    const unsigned short* __restrict__ qk,
    const unsigned short* __restrict__ vt,
    const float* __restrict__ biasT,
    unsigned short* __restrict__ ctxb)
{
    const int qt = blockIdx.x, h = blockIdx.y, b = blockIdx.z;
    const int t = threadIdx.x;
    const int w = t >> 6, lane = t & 63, quad = lane >> 4, l16 = lane & 15;
    const int q0 = qt * 128;

    __shared__ __align__(16) unsigned short smem[128 * FST];   // Qs (prologue) overlays Ks|Vts
    __shared__ __align__(16) unsigned short Pb[128 * FST];
    __shared__ float bias_s[192];
    unsigned short* Qs  = smem;
    unsigned short* Ks  = smem;
    unsigned short* Vts = smem + 64 * FST;

    // stage Q (128 x 64 bf16)
    for (int s = 0; s < 4; s++) {
        int g = t + s * 256;
        int r = g >> 3, c = (g & 7) * 8;
        *(int4*)&Qs[r * FST + c] =
            *(const int4*)(qk + (size_t)(b * S_LEN + q0 + r) * 2048 + h * 64 + c);
    }
    __syncthreads();
    // Q as B-operand, register-resident: [n = q][k]
    bf16x8 qb[2][2];
    for (int nt = 0; nt < 2; nt++)
        for (int ks = 0; ks < 2; ks++)
            qb[ks][nt] = *(const bf16x8*)&Qs[(w * 32 + nt * 16 + l16) * FST + ks * 32 + quad * 8];

    float rsum[2] = {0.f, 0.f};
    f32x4 ctx[4][2] = {};   // ctx^T: [d-tile nd][n-tile nt]

    const float* biasRow = biasT + h * NB_DELTA + 2047;

    for (int kt = 0; kt < S_LEN; kt += 64) {
        __syncthreads();   // previous tile consumed (also protects Qs overlay)
        {
            int r0 = t >> 3, c0 = (t & 7) * 8;
            int g1 = t + 256;
            int r1 = g1 >> 3, c1 = (g1 & 7) * 8;
            const unsigned short* kbase = qk + (size_t)(b * S_LEN + kt) * 2048 + 1024 + h * 64;
            *(int4*)&Ks[r0 * FST + c0] = *(const int4*)(kbase + (size_t)r0 * 2048 + c0);
            *(int4*)&Ks[r1 * FST + c1] = *(const int4*)(kbase + (size_t)r1 * 2048 + c1);
            const unsigned short* vbase = vt + (size_t)(b * 1024 + h * 64) * 2048 + kt;
            *(int4*)&Vts[r0 * FST + c0] = *(const int4*)(vbase + (size_t)r0 * 2048 + c0);
            *(int4*)&Vts[r1 * FST + c1] = *(const int4*)(vbase + (size_t)r1 * 2048 + c1);
            if (t < 192) bias_s[t] = biasRow[kt - q0 - 127 + t] - 16.0f;
        }
        __syncthreads();

        // S^T = K Q^T : A = K rows (m=j), B = Q (n=q); each ka feeds both n-tiles
        f32x4 st[4][2] = {};
        for (int ks = 0; ks < 2; ks++)
            for (int nb = 0; nb < 4; nb++) {
                bf16x8 ka = *(const bf16x8*)&Ks[(nb * 16 + l16) * FST + ks * 32 + quad * 8];
                st[nb][0] = __builtin_amdgcn_mfma_f32_16x16x32_bf16(ka, qb[ks][0], st[nb][0], 0, 0, 0);
                st[nb][1] = __builtin_amdgcn_mfma_f32_16x16x32_bf16(ka, qb[ks][1], st[nb][1], 0, 0, 0);
            }
        // bias + exp (lane-local rowsum), pack P^T
        for (int nt = 0; nt < 2; nt++) {
            const int ib = quad * 4 + 127 - w * 32 - nt * 16 - l16;
            float rs = 0.f;
            for (int nb = 0; nb < 4; nb++) {
                float e0 = __expf(st[nb][nt][0] + bias_s[ib + nb * 16 + 0]);
                float e1 = __expf(st[nb][nt][1] + bias_s[ib + nb * 16 + 1]);
                float e2 = __expf(st[nb][nt][2] + bias_s[ib + nb * 16 + 2]);
                float e3 = __expf(st[nb][nt][3] + bias_s[ib + nb * 16 + 3]);
                rs += (e0 + e1) + (e2 + e3);
                ushort4 pk;
                pk.x = f2bf_fast(e0); pk.y = f2bf_fast(e1);
                pk.z = f2bf_fast(e2); pk.w = f2bf_fast(e3);
                *(ushort4*)&Pb[(w * 32 + nt * 16 + l16) * FST + nb * 16 + quad * 4] = pk;
            }
            rsum[nt] += rs;
        }
        // ctx^T += Vt · P^T : each va feeds both n-tiles
        for (int ks = 0; ks < 2; ks++) {
            bf16x8 pb0 = *(const bf16x8*)&Pb[(w * 32 + l16) * FST + ks * 32 + quad * 8];
            bf16x8 pb1 = *(const bf16x8*)&Pb[(w * 32 + 16 + l16) * FST + ks * 32 + quad * 8];
            for (int nd = 0; nd < 4; nd++) {
                bf16x8 va = *(const bf16x8*)&Vts[(nd * 16 + l16) * FST + ks * 32 + quad * 8];
                ctx[nd][0] = __builtin_amdgcn_mfma_f32_16x16x32_bf16(va, pb0, ctx[nd][0], 0, 0, 0);
                ctx[nd][1] = __builtin_amdgcn_mfma_f32_16x16x32_bf16(va, pb1, ctx[nd][1], 0, 0, 0);
            }
        }
    }
    // epilogue
    for (int nt = 0; nt < 2; nt++) {
        float rs = rsum[nt];
        rs += __shfl_xor(rs, 16, 64);
        rs += __shfl_xor(rs, 32, 64);
        float inv = 1.f / rs;
        size_t row = (size_t)(b * S_LEN + q0 + w * 32 + nt * 16 + l16);
        for (int nd = 0; nd < 4; nd++) {
            ushort4 pk;
            pk.x = f2bf(ctx[nd][nt][0] * inv); pk.y = f2bf(ctx[nd][nt][1] * inv);
            pk.z = f2bf(ctx[nd][nt][2] * inv); pk.w = f2bf(ctx[nd][nt][3] * inv);
            *(ushort4*)&ctxb[row * 1024 + h * 64 + nd * 16 + quad * 4] = pk;
        }
    }
}

extern "C" void kernel_launch(void* const* d_in, const int* in_sizes, int n_in,
                              void* d_out, int out_size, void* d_ws, size_t ws_size,
                              hipStream_t stream) {
    const float* hs       = (const float*)d_in[0];
    const float* Wq       = (const float*)d_in[1];
    const float* Wk       = (const float*)d_in[2];
    const float* Wv       = (const float*)d_in[3];
    const float* Wo       = (const float*)d_in[4];
    const float* rel_bias = (const float*)d_in[5];
    float* out = (float*)d_out;

    char* ws = (char*)d_ws;
    float* biasT          = (float*)ws;           ws += 262144;      // 16*4095*4 (+pad)
    unsigned short* hsb   = (unsigned short*)ws;  ws += 8388608;     // 4096x1024 bf16
    unsigned short* WT    = (unsigned short*)ws;  ws += 6291456;     // [Wq^T|Wk^T|Wv^T] 3072x1024
    unsigned short* WoT   = (unsigned short*)ws;  ws += 2097152;     // 1024x1024 bf16
    unsigned short* qkbuf = (unsigned short*)ws;  ws += 16777216;    // 4096x2048 bf16
    unsigned short* Vtg   = (unsigned short*)ws;  ws += 8388608;     // 2048x2048 bf16
    unsigned short* ctxb  = (unsigned short*)ws;                     // 4096x1024 bf16

    bias_table_kernel<<<(NB_DELTA + 255) / 256, 256, 0, stream>>>(rel_bias, biasT);
    cast_bf16_kernel<<<4096, 256, 0, stream>>>(hs, hsb, 4194304);
    transpose_cast4_kernel<<<dim3(32, 32, 4), 256, 0, stream>>>(
        Wq, Wk, Wv, Wo, WT, WT + 1024 * 1024, WT + 2 * 1024 * 1024, WoT);

    // fused Q|K|V projection: cols<2048 -> qkbuf row-major, cols>=2048 -> Vtg transposed
    gemm_bt_kernel<1><<<dim3(24, 32), 256, 0, stream>>>(hsb, WT, nullptr, qkbuf, Vtg, 1024, 0);
    // attention
    flash4_kernel<<<dim3(S_LEN / 128, NH, 2), 256, 0, stream>>>(qkbuf, Vtg, biasT, ctxb);
    // output projection -> fp32
    gemm_bt_kernel<0><<<dim3(8, 32), 256, 0, stream>>>(ctxb, WoT, out, nullptr, nullptr, 1024, 1024);
}

// Round 5
// 211.641 us; speedup vs baseline: 12.8832x; 1.0677x over previous
//
#include <hip/hip_runtime.h>
#include <stdint.h>

#define S_LEN 2048
#define NH 16
#define NB_DELTA (2*S_LEN-1)   // 4095
#define FST 72                 // flash LDS row stride in bf16 elems

typedef __attribute__((ext_vector_type(8))) __bf16 bf16x8;
typedef __attribute__((ext_vector_type(4))) float f32x4;

__device__ __forceinline__ unsigned short f2bf(float f){   // RNE
    union { float f; unsigned int u; } v; v.f = f;
    unsigned int u = v.u;
    return (unsigned short)((u + 0x7FFFu + ((u >> 16) & 1u)) >> 16);
}
__device__ __forceinline__ unsigned short f2bf_fast(float f){   // round-half-up
    union { float f; unsigned int u; } v; v.f = f;
    return (unsigned short)((v.u + 0x8000u) >> 16);
}

// async global->LDS, 16B per lane; LDS dest = wave-uniform base + lane*16
__device__ __forceinline__ void gload16(const void* g, void* l){
    __builtin_amdgcn_global_load_lds(
        (const __attribute__((address_space(1))) void*)(uintptr_t)g,
        (__attribute__((address_space(3))) void*)(uintptr_t)l, 16, 0, 0);
}

// ---------------- fp32 -> bf16 cast, with bias-table build folded into blocks 0..15
__global__ __launch_bounds__(256) void cast_bias_kernel(const float* __restrict__ in,
                                                        unsigned short* __restrict__ out, int n,
                                                        const float* __restrict__ rel_bias,
                                                        float* __restrict__ biasT){
    int i = (blockIdx.x * blockDim.x + threadIdx.x) * 4;
    if (i < n) {
        float4 f = *(const float4*)(in + i);
        ushort4 o;
        o.x = f2bf(f.x); o.y = f2bf(f.y); o.z = f2bf(f.z); o.w = f2bf(f.w);
        *(ushort4*)(out + i) = o;
    }
    if (blockIdx.x < 16) {
        int t = blockIdx.x * 256 + threadIdx.x;
        if (t < NB_DELTA) {
            int delta = t - (S_LEN - 1);          // j - i
            int bucket = (delta > 0) ? 16 : 0;
            int a = delta < 0 ? -delta : delta;
            int b;
            if (a < 8) b = a;
            else {
                int bl = 33 - __builtin_clz(a * a);   // 8 + floor(2*log2(a/8)), exact
                b = bl < 15 ? bl : 15;
            }
            bucket += b;
            for (int h = 0; h < NH; h++)
                biasT[h * NB_DELTA + t] = rel_bias[bucket * NH + h];
        }
    }
}

// ---------------- fused transpose+cast of the 4 weight matrices (1024x1024 each)
__global__ __launch_bounds__(256) void transpose_cast4_kernel(
    const float* __restrict__ W0, const float* __restrict__ W1,
    const float* __restrict__ W2, const float* __restrict__ W3,
    unsigned short* __restrict__ D0, unsigned short* __restrict__ D1,
    unsigned short* __restrict__ D2, unsigned short* __restrict__ D3){
    const float* src; unsigned short* dst;
    switch (blockIdx.z) {
        case 0: src = W0; dst = D0; break;
        case 1: src = W1; dst = D1; break;
        case 2: src = W2; dst = D2; break;
        default: src = W3; dst = D3; break;
    }
    __shared__ float tile[32][33];
    int bx = blockIdx.x, by = blockIdx.y;
    int tx = threadIdx.x & 31, ty = threadIdx.x >> 5;
    for (int i = 0; i < 4; i++)
        tile[ty + 8*i][tx] = src[(size_t)(by*32 + ty + 8*i) * 1024 + bx*32 + tx];
    __syncthreads();
    for (int i = 0; i < 4; i++)
        dst[(size_t)(bx*32 + ty + 8*i) * 1024 + by*32 + tx] = f2bf(tile[tx][ty + 8*i]);
}

// ---------------- bf16 MFMA GEMM, global_load_lds staging, BN=128, BM templated.
// C[m][n] = sum_k A[m][k] * BT[n][k]; unpadded 64B LDS rows.
// MODE 0: fp32 row-major into C0 (ldc).
// MODE 1: cols<2048 -> bf16 row-major into C1 (ldc=2048); cols>=2048 -> transposed
//         bf16 into C2: Vt[(batch*1024 + (c-2048))][2048 tokens].
template<int MODE, int BM>
__global__ __launch_bounds__(256) void gemm_bt_kernel(const unsigned short* __restrict__ A,
                                                      const unsigned short* __restrict__ BT,
                                                      float* __restrict__ C0,
                                                      unsigned short* __restrict__ C1,
                                                      unsigned short* __restrict__ C2,
                                                      int Kdim, int ldc){
    constexpr int IT = BM / 32;     // m-tiles per wave
    __shared__ __align__(16) unsigned short As[BM * 32];
    __shared__ __align__(16) unsigned short Bs[128 * 32];
    const int t = threadIdx.x;
    const int wave = t >> 6, lane = t & 63;
    const int quad = lane >> 4, l16 = lane & 15;
    const int wm = (wave >> 1) * (BM / 2), wn = (wave & 1) * 64;
    const size_t row0 = (size_t)blockIdx.y * BM, col0 = (size_t)blockIdx.x * 128;

    const unsigned short* ga = A  + (row0 + wave * (BM/4) + (lane >> 2)) * (size_t)Kdim + (lane & 3) * 8;
    const unsigned short* gb = BT + (col0 + wave * 32 + (lane >> 2)) * (size_t)Kdim + (lane & 3) * 8;
    unsigned short* la0 = &As[(wave * (BM/4)) * 32];
    unsigned short* la1 = &As[(wave * (BM/4) + 16) * 32];
    unsigned short* lb0 = &Bs[(wave * 32) * 32];
    unsigned short* lb1 = &Bs[(wave * 32 + 16) * 32];
    const size_t rstep = (size_t)16 * Kdim;

    f32x4 acc[IT][4] = {};

    for (int kt = 0; kt < Kdim; kt += 32) {
        gload16(ga + kt, la0);
        if (BM == 128) gload16(ga + rstep + kt, la1);
        gload16(gb + kt,         lb0);
        gload16(gb + rstep + kt, lb1);
        __syncthreads();
        bf16x8 a[IT], b[4];
        for (int i = 0; i < IT; i++)
            a[i] = *(const bf16x8*)(&As[(wm + i*16 + l16) * 32 + quad * 8]);
        for (int j = 0; j < 4; j++)
            b[j] = *(const bf16x8*)(&Bs[(wn + j*16 + l16) * 32 + quad * 8]);
        for (int i = 0; i < IT; i++)
            for (int j = 0; j < 4; j++)
                acc[i][j] = __builtin_amdgcn_mfma_f32_16x16x32_bf16(a[i], b[j], acc[i][j], 0, 0, 0);
        __syncthreads();
    }
    // C/D layout: col = lane&15, row = quad*4 + reg
    for (int i = 0; i < IT; i++)
        for (int j = 0; j < 4; j++) {
            size_t r0 = row0 + wm + i*16 + quad*4;
            size_t c  = col0 + wn + j*16 + l16;
            if (MODE == 0) {
                for (int r = 0; r < 4; r++)
                    C0[(r0 + r) * ldc + c] = acc[i][j][r];
            } else {
                if (c < 2048) {
                    for (int r = 0; r < 4; r++)
                        C1[(r0 + r) * 2048 + c] = f2bf(acc[i][j][r]);
                } else {
                    int bb = (int)(r0 >> 11);
                    int s  = (int)(r0 & 2047);
                    ushort4 pk;
                    pk.x = f2bf(acc[i][j][0]); pk.y = f2bf(acc[i][j][1]);
                    pk.z = f2bf(acc[i][j][2]); pk.w = f2bf(acc[i][j][3]);
                    *(ushort4*)(C2 + ((size_t)(bb * 1024) + (c - 2048)) * 2048 + s) = pk;
                }
            }
        }
}

// ---------------- MFMA flash attention, S^T form, no-max softmax, SPLIT-S x2.
// grid (S/128, NH, B*2): z = b*2 + chunk; chunk handles keys [ck*1024, ck*1024+1024).
// Partials are additive (no max): ctxp fp32 unnormalized, rsbuf per-(q,h) sums.
__global__ __launch_bounds__(256, 4) void flash5_kernel(
    const unsigned short* __restrict__ qk,
    const unsigned short* __restrict__ vt,
    const float* __restrict__ biasT,
    float* __restrict__ ctxp,          // [2][4096][1024] fp32
    float* __restrict__ rsbuf)         // [2][4096][16]  fp32
{
    const int qt = blockIdx.x, h = blockIdx.y;
    const int b = blockIdx.z >> 1, ck = blockIdx.z & 1;
    const int kt0 = ck << 10;
    const int t = threadIdx.x;
    const int w = t >> 6, lane = t & 63, quad = lane >> 4, l16 = lane & 15;
    const int q0 = qt * 128;

    __shared__ __align__(16) unsigned short smem[128 * FST];   // Qs (prologue) overlays Ks|Vts
    __shared__ __align__(16) unsigned short Pb[128 * FST];
    __shared__ float bias_s[192];
    unsigned short* Qs  = smem;
    unsigned short* Ks  = smem;
    unsigned short* Vts = smem + 64 * FST;

    // stage Q (128 x 64 bf16)
    for (int s = 0; s < 4; s++) {
        int g = t + s * 256;
        int r = g >> 3, c = (g & 7) * 8;
        *(int4*)&Qs[r * FST + c] =
            *(const int4*)(qk + (size_t)(b * S_LEN + q0 + r) * 2048 + h * 64 + c);
    }
    __syncthreads();
    bf16x8 qb[2][2];
    for (int nt = 0; nt < 2; nt++)
        for (int ks = 0; ks < 2; ks++)
            qb[ks][nt] = *(const bf16x8*)&Qs[(w * 32 + nt * 16 + l16) * FST + ks * 32 + quad * 8];

    float rsum[2] = {0.f, 0.f};
    f32x4 ctx[4][2] = {};   // ctx^T: [d-tile nd][n-tile nt]

    const float* biasRow = biasT + h * NB_DELTA + 2047;

    for (int kt = kt0; kt < kt0 + 1024; kt += 64) {
        __syncthreads();   // previous tile consumed (also protects Qs overlay)
        {
            int r0 = t >> 3, c0 = (t & 7) * 8;
            int g1 = t + 256;
            int r1 = g1 >> 3, c1 = (g1 & 7) * 8;
            const unsigned short* kbase = qk + (size_t)(b * S_LEN + kt) * 2048 + 1024 + h * 64;
            *(int4*)&Ks[r0 * FST + c0] = *(const int4*)(kbase + (size_t)r0 * 2048 + c0);
            *(int4*)&Ks[r1 * FST + c1] = *(const int4*)(kbase + (size_t)r1 * 2048 + c1);
            const unsigned short* vbase = vt + (size_t)(b * 1024 + h * 64) * 2048 + kt;
            *(int4*)&Vts[r0 * FST + c0] = *(const int4*)(vbase + (size_t)r0 * 2048 + c0);
            *(int4*)&Vts[r1 * FST + c1] = *(const int4*)(vbase + (size_t)r1 * 2048 + c1);
            if (t < 192) bias_s[t] = biasRow[kt - q0 - 127 + t] - 16.0f;
        }
        __syncthreads();

        // S^T = K Q^T : A = K rows (m=j), B = Q (n=q); each ka feeds both n-tiles
        f32x4 st[4][2] = {};
        for (int ks = 0; ks < 2; ks++)
            for (int nb = 0; nb < 4; nb++) {
                bf16x8 ka = *(const bf16x8*)&Ks[(nb * 16 + l16) * FST + ks * 32 + quad * 8];
                st[nb][0] = __builtin_amdgcn_mfma_f32_16x16x32_bf16(ka, qb[ks][0], st[nb][0], 0, 0, 0);
                st[nb][1] = __builtin_amdgcn_mfma_f32_16x16x32_bf16(ka, qb[ks][1], st[nb][1], 0, 0, 0);
            }
        // bias + exp (lane-local rowsum), pack P^T
        for (int nt = 0; nt < 2; nt++) {
            const int ib = quad * 4 + 127 - w * 32 - nt * 16 - l16;
            float rs = 0.f;
            for (int nb = 0; nb < 4; nb++) {
                float e0 = __expf(st[nb][nt][0] + bias_s[ib + nb * 16 + 0]);
                float e1 = __expf(st[nb][nt][1] + bias_s[ib + nb * 16 + 1]);
                float e2 = __expf(st[nb][nt][2] + bias_s[ib + nb * 16 + 2]);
                float e3 = __expf(st[nb][nt][3] + bias_s[ib + nb * 16 + 3]);
                rs += (e0 + e1) + (e2 + e3);
                ushort4 pk;
                pk.x = f2bf_fast(e0); pk.y = f2bf_fast(e1);
                pk.z = f2bf_fast(e2); pk.w = f2bf_fast(e3);
                *(ushort4*)&Pb[(w * 32 + nt * 16 + l16) * FST + nb * 16 + quad * 4] = pk;
            }
            rsum[nt] += rs;
        }
        // ctx^T += Vt · P^T : each va feeds both n-tiles
        for (int ks = 0; ks < 2; ks++) {
            bf16x8 pb0 = *(const bf16x8*)&Pb[(w * 32 + l16) * FST + ks * 32 + quad * 8];
            bf16x8 pb1 = *(const bf16x8*)&Pb[(w * 32 + 16 + l16) * FST + ks * 32 + quad * 8];
            for (int nd = 0; nd < 4; nd++) {
                bf16x8 va = *(const bf16x8*)&Vts[(nd * 16 + l16) * FST + ks * 32 + quad * 8];
                ctx[nd][0] = __builtin_amdgcn_mfma_f32_16x16x32_bf16(va, pb0, ctx[nd][0], 0, 0, 0);
                ctx[nd][1] = __builtin_amdgcn_mfma_f32_16x16x32_bf16(va, pb1, ctx[nd][1], 0, 0, 0);
            }
        }
    }
    // epilogue: store UNNORMALIZED fp32 partials + row sums
    float* cp = ctxp + (size_t)ck * 4096 * 1024;
    for (int nt = 0; nt < 2; nt++) {
        float rs = rsum[nt];
        rs += __shfl_xor(rs, 16, 64);
        rs += __shfl_xor(rs, 32, 64);
        int row = b * S_LEN + q0 + w * 32 + nt * 16 + l16;
        if (quad == 0) rsbuf[((size_t)ck * 4096 + row) * 16 + h] = rs;
        for (int nd = 0; nd < 4; nd++) {
            float4 pv;
            pv.x = ctx[nd][nt][0]; pv.y = ctx[nd][nt][1];
            pv.z = ctx[nd][nt][2]; pv.w = ctx[nd][nt][3];
            *(float4*)&cp[(size_t)row * 1024 + h * 64 + nd * 16 + quad * 4] = pv;
        }
    }
}

// ---------------- combine: ctx_bf16 = (ctx0 + ctx1) / (l0 + l1)
__global__ __launch_bounds__(256) void combine_kernel(const float* __restrict__ ctxp,
                                                      const float* __restrict__ rsbuf,
                                                      unsigned short* __restrict__ ctxb){
    int e = blockIdx.x * 256 + threadIdx.x;     // one float4 per thread
    int row = e >> 8;
    int c4 = (e & 255) * 4;
    int h = c4 >> 6;
    float l = rsbuf[(size_t)row * 16 + h] + rsbuf[((size_t)4096 + row) * 16 + h];
    float4 a = *(const float4*)&ctxp[(size_t)row * 1024 + c4];
    float4 bb = *(const float4*)&ctxp[(size_t)4096 * 1024 + (size_t)row * 1024 + c4];
    float inv = 1.f / l;
    ushort4 o;
    o.x = f2bf((a.x + bb.x) * inv); o.y = f2bf((a.y + bb.y) * inv);
    o.z = f2bf((a.z + bb.z) * inv); o.w = f2bf((a.w + bb.w) * inv);
    *(ushort4*)&ctxb[(size_t)row * 1024 + c4] = o;
}

extern "C" void kernel_launch(void* const* d_in, const int* in_sizes, int n_in,
                              void* d_out, int out_size, void* d_ws, size_t ws_size,
                              hipStream_t stream) {
    const float* hs       = (const float*)d_in[0];
    const float* Wq       = (const float*)d_in[1];
    const float* Wk       = (const float*)d_in[2];
    const float* Wv       = (const float*)d_in[3];
    const float* Wo       = (const float*)d_in[4];
    const float* rel_bias = (const float*)d_in[5];
    float* out = (float*)d_out;

    char* ws = (char*)d_ws;
    float* biasT          = (float*)ws;           ws += 262144;      // 16*4095*4 (+pad)
    unsigned short* hsb   = (unsigned short*)ws;  ws += 8388608;     // 4096x1024 bf16
    unsigned short* WT    = (unsigned short*)ws;  ws += 6291456;     // [Wq^T|Wk^T|Wv^T] 3072x1024
    unsigned short* WoT   = (unsigned short*)ws;  ws += 2097152;     // 1024x1024 bf16
    unsigned short* qkbuf = (unsigned short*)ws;  ws += 16777216;    // 4096x2048 bf16
    unsigned short* Vtg   = (unsigned short*)ws;  ws += 8388608;     // 2048x2048 bf16
    unsigned short* ctxb  = (unsigned short*)ws;  ws += 8388608;     // 4096x1024 bf16
    float* ctxp           = (float*)ws;           ws += 33554432;    // 2 x 4096x1024 fp32
    float* rsbuf          = (float*)ws;                              // 2 x 4096x16 fp32

    cast_bias_kernel<<<4096, 256, 0, stream>>>(hs, hsb, 4194304, rel_bias, biasT);
    transpose_cast4_kernel<<<dim3(32, 32, 4), 256, 0, stream>>>(
        Wq, Wk, Wv, Wo, WT, WT + 1024 * 1024, WT + 2 * 1024 * 1024, WoT);

    // fused Q|K|V projection: cols<2048 -> qkbuf row-major, cols>=2048 -> Vtg transposed
    gemm_bt_kernel<1, 128><<<dim3(24, 32), 256, 0, stream>>>(hsb, WT, nullptr, qkbuf, Vtg, 1024, 0);
    // attention, split-S x2
    flash5_kernel<<<dim3(S_LEN / 128, NH, 4), 256, 0, stream>>>(qkbuf, Vtg, biasT, ctxp, rsbuf);
    // combine partials -> bf16 ctx
    combine_kernel<<<4096, 256, 0, stream>>>(ctxp, rsbuf, ctxb);
    // output projection -> fp32 (BM=64: 512 blocks, 2/CU)
    gemm_bt_kernel<0, 64><<<dim3(8, 64), 256, 0, stream>>>(ctxb, WoT, out, nullptr, nullptr, 1024, 1024);
}

// Round 6
// 208.951 us; speedup vs baseline: 13.0491x; 1.0129x over previous
//
#include <hip/hip_runtime.h>
#include <stdint.h>

#define S_LEN 2048
#define NH 16
#define NB_DELTA (2*S_LEN-1)   // 4095
#define PST 72                 // P LDS row stride in bf16 elems

typedef __attribute__((ext_vector_type(8))) __bf16 bf16x8;
typedef __attribute__((ext_vector_type(4))) float f32x4;

__device__ __forceinline__ unsigned short f2bf(float f){   // RNE
    union { float f; unsigned int u; } v; v.f = f;
    unsigned int u = v.u;
    return (unsigned short)((u + 0x7FFFu + ((u >> 16) & 1u)) >> 16);
}
__device__ __forceinline__ unsigned short f2bf_fast(float f){   // round-half-up
    union { float f; unsigned int u; } v; v.f = f;
    return (unsigned short)((v.u + 0x8000u) >> 16);
}
__device__ __forceinline__ float bf2f(unsigned short u){
    union { unsigned int u; float f; } v; v.u = ((unsigned int)u) << 16;
    return v.f;
}

// async global->LDS, 16B per lane; LDS dest = wave-uniform base + lane*16
__device__ __forceinline__ void gload16(const void* g, void* l){
    __builtin_amdgcn_global_load_lds(
        (const __attribute__((address_space(1))) void*)(uintptr_t)g,
        (__attribute__((address_space(3))) void*)(uintptr_t)l, 16, 0, 0);
}

// ---------------- fused prep: z<4 -> transpose+cast W[z]; z==4 -> hs cast + bias table
__global__ __launch_bounds__(256) void prep_kernel(
    const float* __restrict__ hs, unsigned short* __restrict__ hsb,
    const float* __restrict__ W0, const float* __restrict__ W1,
    const float* __restrict__ W2, const float* __restrict__ W3,
    unsigned short* __restrict__ D0, unsigned short* __restrict__ D1,
    unsigned short* __restrict__ D2, unsigned short* __restrict__ D3,
    const float* __restrict__ rel_bias, float* __restrict__ biasT){
    if (blockIdx.z == 4) {
        int bi = blockIdx.y * 32 + blockIdx.x;   // 0..1023
        for (int it = 0; it < 4; it++) {
            int i = bi * 4096 + it * 1024 + threadIdx.x * 4;
            float4 f = *(const float4*)(hs + i);
            ushort4 o;
            o.x = f2bf(f.x); o.y = f2bf(f.y); o.z = f2bf(f.z); o.w = f2bf(f.w);
            *(ushort4*)(hsb + i) = o;
        }
        if (bi < 16) {
            int t = bi * 256 + threadIdx.x;
            if (t < NB_DELTA) {
                int delta = t - (S_LEN - 1);          // j - i
                int bucket = (delta > 0) ? 16 : 0;
                int a = delta < 0 ? -delta : delta;
                int b;
                if (a < 8) b = a;
                else {
                    int bl = 33 - __builtin_clz(a * a);   // 8 + floor(2*log2(a/8)), exact
                    b = bl < 15 ? bl : 15;
                }
                bucket += b;
                for (int h = 0; h < NH; h++)
                    biasT[h * NB_DELTA + t] = rel_bias[bucket * NH + h];
            }
        }
        return;
    }
    const float* src; unsigned short* dst;
    switch (blockIdx.z) {
        case 0: src = W0; dst = D0; break;
        case 1: src = W1; dst = D1; break;
        case 2: src = W2; dst = D2; break;
        default: src = W3; dst = D3; break;
    }
    __shared__ float tile[32][33];
    int bx = blockIdx.x, by = blockIdx.y;
    int tx = threadIdx.x & 31, ty = threadIdx.x >> 5;
    for (int i = 0; i < 4; i++)
        tile[ty + 8*i][tx] = src[(size_t)(by*32 + ty + 8*i) * 1024 + bx*32 + tx];
    __syncthreads();
    for (int i = 0; i < 4; i++)
        dst[(size_t)(bx*32 + ty + 8*i) * 1024 + by*32 + tx] = f2bf(tile[tx][ty + 8*i]);
}

// ---------------- bf16 MFMA GEMM, global_load_lds staging, BN=128, BM templated.
// MODE 0: fp32 row-major into C0 (ldc).
// MODE 1: cols<2048 -> bf16 row-major into C1 (ldc=2048); cols>=2048 -> transposed
//         bf16 into C2: Vt[(batch*1024 + (c-2048))][2048 tokens].
template<int MODE, int BM>
__global__ __launch_bounds__(256) void gemm_bt_kernel(const unsigned short* __restrict__ A,
                                                      const unsigned short* __restrict__ BT,
                                                      float* __restrict__ C0,
                                                      unsigned short* __restrict__ C1,
                                                      unsigned short* __restrict__ C2,
                                                      int Kdim, int ldc){
    constexpr int IT = BM / 32;     // m-tiles per wave
    __shared__ __align__(16) unsigned short As[BM * 32];
    __shared__ __align__(16) unsigned short Bs[128 * 32];
    const int t = threadIdx.x;
    const int wave = t >> 6, lane = t & 63;
    const int quad = lane >> 4, l16 = lane & 15;
    const int wm = (wave >> 1) * (BM / 2), wn = (wave & 1) * 64;
    const size_t row0 = (size_t)blockIdx.y * BM, col0 = (size_t)blockIdx.x * 128;

    const unsigned short* ga = A  + (row0 + wave * (BM/4) + (lane >> 2)) * (size_t)Kdim + (lane & 3) * 8;
    const unsigned short* gb = BT + (col0 + wave * 32 + (lane >> 2)) * (size_t)Kdim + (lane & 3) * 8;
    unsigned short* la0 = &As[(wave * (BM/4)) * 32];
    unsigned short* la1 = &As[(wave * (BM/4) + 16) * 32];
    unsigned short* lb0 = &Bs[(wave * 32) * 32];
    unsigned short* lb1 = &Bs[(wave * 32 + 16) * 32];
    const size_t rstep = (size_t)16 * Kdim;

    f32x4 acc[IT][4] = {};

    for (int kt = 0; kt < Kdim; kt += 32) {
        gload16(ga + kt, la0);
        if (BM == 128) gload16(ga + rstep + kt, la1);
        gload16(gb + kt,         lb0);
        gload16(gb + rstep + kt, lb1);
        __syncthreads();
        bf16x8 a[IT], b[4];
        for (int i = 0; i < IT; i++)
            a[i] = *(const bf16x8*)(&As[(wm + i*16 + l16) * 32 + quad * 8]);
        for (int j = 0; j < 4; j++)
            b[j] = *(const bf16x8*)(&Bs[(wn + j*16 + l16) * 32 + quad * 8]);
        for (int i = 0; i < IT; i++)
            for (int j = 0; j < 4; j++)
                acc[i][j] = __builtin_amdgcn_mfma_f32_16x16x32_bf16(a[i], b[j], acc[i][j], 0, 0, 0);
        __syncthreads();
    }
    // C/D layout: col = lane&15, row = quad*4 + reg
    for (int i = 0; i < IT; i++)
        for (int j = 0; j < 4; j++) {
            size_t r0 = row0 + wm + i*16 + quad*4;
            size_t c  = col0 + wn + j*16 + l16;
            if (MODE == 0) {
                for (int r = 0; r < 4; r++)
                    C0[(r0 + r) * ldc + c] = acc[i][j][r];
            } else {
                if (c < 2048) {
                    for (int r = 0; r < 4; r++)
                        C1[(r0 + r) * 2048 + c] = f2bf(acc[i][j][r]);
                } else {
                    int bb = (int)(r0 >> 11);
                    int s  = (int)(r0 & 2047);
                    ushort4 pk;
                    pk.x = f2bf(acc[i][j][0]); pk.y = f2bf(acc[i][j][1]);
                    pk.z = f2bf(acc[i][j][2]); pk.w = f2bf(acc[i][j][3]);
                    *(ushort4*)(C2 + ((size_t)(bb * 1024) + (c - 2048)) * 2048 + s) = pk;
                }
            }
        }
}

// ---------------- MFMA flash attention, S^T form, no-max softmax, split-S x2,
// async global_load_lds K/V staging (m97-style unpadded 64B-row sub-arrays).
// grid (S/128, NH, B*2): z = b*2 + chunk; chunk handles keys [ck*1024, +1024).
// Partials additive: ctxpb bf16 unnormalized, rsbuf per-(q,h) fp32 sums.
__global__ __launch_bounds__(256, 4) void flash6_kernel(
    const unsigned short* __restrict__ qk,
    const unsigned short* __restrict__ vt,
    const float* __restrict__ biasT,
    unsigned short* __restrict__ ctxpb,   // [2][4096][1024] bf16
    float* __restrict__ rsbuf)            // [2][4096][16]  fp32
{
    const int qt = blockIdx.x, h = blockIdx.y;
    const int b = blockIdx.z >> 1, ck = blockIdx.z & 1;
    const int kt0 = ck << 10;
    const int t = threadIdx.x;
    const int w = t >> 6, lane = t & 63, quad = lane >> 4, l16 = lane & 15;
    const int q0 = qt * 128;

    // K/V: 4 sub-arrays 64 rows x 32 cols (64B rows, unpadded -> global_load_lds OK)
    __shared__ __align__(16) unsigned short KV[4][64 * 32];
    __shared__ __align__(16) unsigned short Pb[128 * PST];   // P^T; Q scratch in prologue
    __shared__ float bias_s[192];

    // stage Q (128 x 64 bf16) into Pb scratch (stride PST)
    for (int s = 0; s < 4; s++) {
        int g = t + s * 256;
        int r = g >> 3, c = (g & 7) * 8;
        *(int4*)&Pb[r * PST + c] =
            *(const int4*)(qk + (size_t)(b * S_LEN + q0 + r) * 2048 + h * 64 + c);
    }
    __syncthreads();
    bf16x8 qb[2][2];   // [ks][nt]
    for (int nt = 0; nt < 2; nt++)
        for (int ks = 0; ks < 2; ks++)
            qb[ks][nt] = *(const bf16x8*)&Pb[(w * 32 + nt * 16 + l16) * PST + ks * 32 + quad * 8];

    float rsum[2] = {0.f, 0.f};
    f32x4 ctx[4][2] = {};   // ctx^T: [d-tile nd][n-tile nt]

    const float* biasRow = biasT + h * NB_DELTA + 2047;

    // per-lane global source offsets for async staging: wave w covers rows w*16..+15
    const int srow = w * 16 + (lane >> 2);
    const int scol = (lane & 3) * 8;
    unsigned short* ldsK0 = &KV[0][w * 16 * 32];
    unsigned short* ldsK1 = &KV[1][w * 16 * 32];
    unsigned short* ldsV0 = &KV[2][w * 16 * 32];
    unsigned short* ldsV1 = &KV[3][w * 16 * 32];

    for (int kt = kt0; kt < kt0 + 1024; kt += 64) {
        __syncthreads();   // previous tile consumed (also protects Pb/Q overlay)
        {
            const unsigned short* kb = qk + (size_t)(b * S_LEN + kt + srow) * 2048 + 1024 + h * 64 + scol;
            const unsigned short* vb = vt + (size_t)(b * 1024 + h * 64 + srow) * 2048 + kt + scol;
            gload16(kb,      ldsK0);
            gload16(kb + 32, ldsK1);
            gload16(vb,      ldsV0);
            gload16(vb + 32, ldsV1);
            if (t < 192) bias_s[t] = biasRow[kt - q0 - 127 + t] - 16.0f;
        }
        __syncthreads();

        // S^T = K Q^T : A = K rows (m=j), B = Q (n=q); each ka feeds both n-tiles
        f32x4 st[4][2] = {};
        for (int ks = 0; ks < 2; ks++)
            for (int nb = 0; nb < 4; nb++) {
                bf16x8 ka = *(const bf16x8*)&KV[ks][(nb * 16 + l16) * 32 + quad * 8];
                st[nb][0] = __builtin_amdgcn_mfma_f32_16x16x32_bf16(ka, qb[ks][0], st[nb][0], 0, 0, 0);
                st[nb][1] = __builtin_amdgcn_mfma_f32_16x16x32_bf16(ka, qb[ks][1], st[nb][1], 0, 0, 0);
            }
        // bias + exp (lane-local rowsum), pack P^T
        for (int nt = 0; nt < 2; nt++) {
            const int ib = quad * 4 + 127 - w * 32 - nt * 16 - l16;
            float rs = 0.f;
            for (int nb = 0; nb < 4; nb++) {
                float e0 = __expf(st[nb][nt][0] + bias_s[ib + nb * 16 + 0]);
                float e1 = __expf(st[nb][nt][1] + bias_s[ib + nb * 16 + 1]);
                float e2 = __expf(st[nb][nt][2] + bias_s[ib + nb * 16 + 2]);
                float e3 = __expf(st[nb][nt][3] + bias_s[ib + nb * 16 + 3]);
                rs += (e0 + e1) + (e2 + e3);
                ushort4 pk;
                pk.x = f2bf_fast(e0); pk.y = f2bf_fast(e1);
                pk.z = f2bf_fast(e2); pk.w = f2bf_fast(e3);
                *(ushort4*)&Pb[(w * 32 + nt * 16 + l16) * PST + nb * 16 + quad * 4] = pk;
            }
            rsum[nt] += rs;
        }
        // ctx^T += Vt · P^T : each va feeds both n-tiles
        for (int ks = 0; ks < 2; ks++) {
            bf16x8 pb0 = *(const bf16x8*)&Pb[(w * 32 + l16) * PST + ks * 32 + quad * 8];
            bf16x8 pb1 = *(const bf16x8*)&Pb[(w * 32 + 16 + l16) * PST + ks * 32 + quad * 8];
            for (int nd = 0; nd < 4; nd++) {
                bf16x8 va = *(const bf16x8*)&KV[2 + ks][(nd * 16 + l16) * 32 + quad * 8];
                ctx[nd][0] = __builtin_amdgcn_mfma_f32_16x16x32_bf16(va, pb0, ctx[nd][0], 0, 0, 0);
                ctx[nd][1] = __builtin_amdgcn_mfma_f32_16x16x32_bf16(va, pb1, ctx[nd][1], 0, 0, 0);
            }
        }
    }
    // epilogue: store UNNORMALIZED bf16 partials + fp32 row sums
    unsigned short* cp = ctxpb + (size_t)ck * 4096 * 1024;
    for (int nt = 0; nt < 2; nt++) {
        float rs = rsum[nt];
        rs += __shfl_xor(rs, 16, 64);
        rs += __shfl_xor(rs, 32, 64);
        int row = b * S_LEN + q0 + w * 32 + nt * 16 + l16;
        if (quad == 0) rsbuf[((size_t)ck * 4096 + row) * 16 + h] = rs;
        for (int nd = 0; nd < 4; nd++) {
            ushort4 pk;
            pk.x = f2bf(ctx[nd][nt][0]); pk.y = f2bf(ctx[nd][nt][1]);
            pk.z = f2bf(ctx[nd][nt][2]); pk.w = f2bf(ctx[nd][nt][3]);
            *(ushort4*)&cp[(size_t)row * 1024 + h * 64 + nd * 16 + quad * 4] = pk;
        }
    }
}

// ---------------- combine: ctx_bf16 = (ctx0 + ctx1) / (l0 + l1)
__global__ __launch_bounds__(256) void combine_kernel(const unsigned short* __restrict__ ctxpb,
                                                      const float* __restrict__ rsbuf,
                                                      unsigned short* __restrict__ ctxb){
    int e = blockIdx.x * 256 + threadIdx.x;     // one ushort4 per thread
    int row = e >> 8;
    int c4 = (e & 255) * 4;
    int h = c4 >> 6;
    float l = rsbuf[(size_t)row * 16 + h] + rsbuf[((size_t)4096 + row) * 16 + h];
    ushort4 a  = *(const ushort4*)&ctxpb[(size_t)row * 1024 + c4];
    ushort4 b2 = *(const ushort4*)&ctxpb[(size_t)4096 * 1024 + (size_t)row * 1024 + c4];
    float inv = 1.f / l;
    ushort4 o;
    o.x = f2bf((bf2f(a.x) + bf2f(b2.x)) * inv);
    o.y = f2bf((bf2f(a.y) + bf2f(b2.y)) * inv);
    o.z = f2bf((bf2f(a.z) + bf2f(b2.z)) * inv);
    o.w = f2bf((bf2f(a.w) + bf2f(b2.w)) * inv);
    *(ushort4*)&ctxb[(size_t)row * 1024 + c4] = o;
}

extern "C" void kernel_launch(void* const* d_in, const int* in_sizes, int n_in,
                              void* d_out, int out_size, void* d_ws, size_t ws_size,
                              hipStream_t stream) {
    const float* hs       = (const float*)d_in[0];
    const float* Wq       = (const float*)d_in[1];
    const float* Wk       = (const float*)d_in[2];
    const float* Wv       = (const float*)d_in[3];
    const float* Wo       = (const float*)d_in[4];
    const float* rel_bias = (const float*)d_in[5];
    float* out = (float*)d_out;

    char* ws = (char*)d_ws;
    float* biasT          = (float*)ws;           ws += 262144;      // 16*4095*4 (+pad)
    unsigned short* hsb   = (unsigned short*)ws;  ws += 8388608;     // 4096x1024 bf16
    unsigned short* WT    = (unsigned short*)ws;  ws += 6291456;     // [Wq^T|Wk^T|Wv^T] 3072x1024
    unsigned short* WoT   = (unsigned short*)ws;  ws += 2097152;     // 1024x1024 bf16
    unsigned short* qkbuf = (unsigned short*)ws;  ws += 16777216;    // 4096x2048 bf16
    unsigned short* Vtg   = (unsigned short*)ws;  ws += 8388608;     // 2048x2048 bf16
    unsigned short* ctxb  = (unsigned short*)ws;  ws += 8388608;     // 4096x1024 bf16
    unsigned short* ctxpb = (unsigned short*)ws;  ws += 16777216;    // 2 x 4096x1024 bf16
    float* rsbuf          = (float*)ws;                              // 2 x 4096x16 fp32

    prep_kernel<<<dim3(32, 32, 5), 256, 0, stream>>>(
        hs, hsb, Wq, Wk, Wv, Wo,
        WT, WT + 1024 * 1024, WT + 2 * 1024 * 1024, WoT, rel_bias, biasT);

    // fused Q|K|V projection: cols<2048 -> qkbuf row-major, cols>=2048 -> Vtg transposed
    gemm_bt_kernel<1, 128><<<dim3(24, 32), 256, 0, stream>>>(hsb, WT, nullptr, qkbuf, Vtg, 1024, 0);
    // attention, split-S x2, async staging
    flash6_kernel<<<dim3(S_LEN / 128, NH, 4), 256, 0, stream>>>(qkbuf, Vtg, biasT, ctxpb, rsbuf);
    // combine partials -> bf16 ctx
    combine_kernel<<<4096, 256, 0, stream>>>(ctxpb, rsbuf, ctxb);
    // output projection -> fp32 (BM=64: 512 blocks, 2/CU)
    gemm_bt_kernel<0, 64><<<dim3(8, 64), 256, 0, stream>>>(ctxb, WoT, out, nullptr, nullptr, 1024, 1024);
}

// Round 7
// 207.583 us; speedup vs baseline: 13.1351x; 1.0066x over previous
//
#include <hip/hip_runtime.h>
#include <stdint.h>

#define S_LEN 2048
#define NH 16
#define NB_DELTA (2*S_LEN-1)   // 4095
#define PST 72                 // P LDS row stride in bf16 elems

typedef __attribute__((ext_vector_type(8))) __bf16 bf16x8;
typedef __attribute__((ext_vector_type(4))) float f32x4;

__device__ __forceinline__ unsigned short f2bf(float f){   // RNE
    union { float f; unsigned int u; } v; v.f = f;
    unsigned int u = v.u;
    return (unsigned short)((u + 0x7FFFu + ((u >> 16) & 1u)) >> 16);
}
__device__ __forceinline__ unsigned short f2bf_fast(float f){   // round-half-up
    union { float f; unsigned int u; } v; v.f = f;
    return (unsigned short)((v.u + 0x8000u) >> 16);
}
__device__ __forceinline__ float bf2f(unsigned short u){
    union { unsigned int u; float f; } v; v.u = ((unsigned int)u) << 16;
    return v.f;
}

// async global->LDS, 16B per lane; LDS dest = wave-uniform base + lane*16
__device__ __forceinline__ void gload16(const void* g, void* l){
    __builtin_amdgcn_global_load_lds(
        (const __attribute__((address_space(1))) void*)(uintptr_t)g,
        (__attribute__((address_space(3))) void*)(uintptr_t)l, 16, 0, 0);
}

// ---------------- fused prep: z<4 -> transpose+cast W[z]; z==4 -> hs cast + bias table
__global__ __launch_bounds__(256) void prep_kernel(
    const float* __restrict__ hs, unsigned short* __restrict__ hsb,
    const float* __restrict__ W0, const float* __restrict__ W1,
    const float* __restrict__ W2, const float* __restrict__ W3,
    unsigned short* __restrict__ D0, unsigned short* __restrict__ D1,
    unsigned short* __restrict__ D2, unsigned short* __restrict__ D3,
    const float* __restrict__ rel_bias, float* __restrict__ biasT){
    if (blockIdx.z == 4) {
        int bi = blockIdx.y * 32 + blockIdx.x;   // 0..1023
        for (int it = 0; it < 4; it++) {
            int i = bi * 4096 + it * 1024 + threadIdx.x * 4;
            float4 f = *(const float4*)(hs + i);
            ushort4 o;
            o.x = f2bf(f.x); o.y = f2bf(f.y); o.z = f2bf(f.z); o.w = f2bf(f.w);
            *(ushort4*)(hsb + i) = o;
        }
        if (bi < 16) {
            int t = bi * 256 + threadIdx.x;
            if (t < NB_DELTA) {
                int delta = t - (S_LEN - 1);          // j - i
                int bucket = (delta > 0) ? 16 : 0;
                int a = delta < 0 ? -delta : delta;
                int b;
                if (a < 8) b = a;
                else {
                    int bl = 33 - __builtin_clz(a * a);   // 8 + floor(2*log2(a/8)), exact
                    b = bl < 15 ? bl : 15;
                }
                bucket += b;
                for (int h = 0; h < NH; h++)
                    biasT[h * NB_DELTA + t] = rel_bias[bucket * NH + h];
            }
        }
        return;
    }
    const float* src; unsigned short* dst;
    switch (blockIdx.z) {
        case 0: src = W0; dst = D0; break;
        case 1: src = W1; dst = D1; break;
        case 2: src = W2; dst = D2; break;
        default: src = W3; dst = D3; break;
    }
    __shared__ float tile[32][33];
    int bx = blockIdx.x, by = blockIdx.y;
    int tx = threadIdx.x & 31, ty = threadIdx.x >> 5;
    for (int i = 0; i < 4; i++)
        tile[ty + 8*i][tx] = src[(size_t)(by*32 + ty + 8*i) * 1024 + bx*32 + tx];
    __syncthreads();
    for (int i = 0; i < 4; i++)
        dst[(size_t)(bx*32 + ty + 8*i) * 1024 + by*32 + tx] = f2bf(tile[tx][ty + 8*i]);
}

// ---------------- bf16 MFMA GEMM, BK=64, async staging, XOR-granule-swizzled LDS.
// LDS rows = 128B (8 granules of 16B); granule g of row r stored at slot g^(r&7)
// -> fragment reads are 2-way (free) instead of 8-way conflicted.
// MODE 0: fp32 row-major into C0; MODE 1: bf16 row-major into C1. BN=128, BM templated.
template<int MODE, int BM>
__global__ __launch_bounds__(256) void gemm_bt_kernel(const unsigned short* __restrict__ A,
                                                      const unsigned short* __restrict__ BT,
                                                      float* __restrict__ C0,
                                                      unsigned short* __restrict__ C1,
                                                      int Kdim, int ldc){
    constexpr int IT = BM / 32;     // m-tiles per wave
    __shared__ __align__(16) unsigned short As[BM * 64];
    __shared__ __align__(16) unsigned short Bs[128 * 64];
    const int t = threadIdx.x;
    const int wave = t >> 6, lane = t & 63;
    const int quad = lane >> 4, l16 = lane & 15;
    const int wm = (wave >> 1) * (BM / 2), wn = (wave & 1) * 64;
    const size_t row0 = (size_t)blockIdx.y * BM, col0 = (size_t)blockIdx.x * 128;

    const int srow8 = lane >> 3;                 // 0..7: row within the wave's 8-row group
    const int gg = (lane & 7) ^ srow8;           // fetch-side granule remap (row&7 == srow8)
    const unsigned short* gA = A  + (row0 + wave * 8 + srow8) * (size_t)Kdim + gg * 8;
    const unsigned short* gB = BT + (col0 + wave * 8 + srow8) * (size_t)Kdim + gg * 8;

    f32x4 acc[IT][4] = {};

    for (int kt = 0; kt < Kdim; kt += 64) {
        for (int p = 0; p < BM / 32; p++)
            gload16(gA + (size_t)(p * 32) * Kdim + kt, &As[(p * 32 + wave * 8) * 64]);
        for (int p = 0; p < 4; p++)
            gload16(gB + (size_t)(p * 32) * Kdim + kt, &Bs[(p * 32 + wave * 8) * 64]);
        __syncthreads();
        bf16x8 a[2][IT], b[2][4];
        for (int ks = 0; ks < 2; ks++) {
            for (int i = 0; i < IT; i++)
                a[ks][i] = *(const bf16x8*)(&As[(wm + i*16 + l16) * 64 + (((ks*4 + quad) ^ (l16 & 7)) * 8)]);
            for (int j = 0; j < 4; j++)
                b[ks][j] = *(const bf16x8*)(&Bs[(wn + j*16 + l16) * 64 + (((ks*4 + quad) ^ (l16 & 7)) * 8)]);
        }
        for (int ks = 0; ks < 2; ks++)
            for (int i = 0; i < IT; i++)
                for (int j = 0; j < 4; j++)
                    acc[i][j] = __builtin_amdgcn_mfma_f32_16x16x32_bf16(a[ks][i], b[ks][j], acc[i][j], 0, 0, 0);
        __syncthreads();
    }
    // C/D layout: col = lane&15, row = quad*4 + reg
    for (int i = 0; i < IT; i++)
        for (int j = 0; j < 4; j++) {
            size_t r0 = row0 + wm + i*16 + quad*4;
            size_t c  = col0 + wn + j*16 + l16;
            if (MODE == 0) {
                for (int r = 0; r < 4; r++)
                    C0[(r0 + r) * ldc + c] = acc[i][j][r];
            } else {
                for (int r = 0; r < 4; r++)
                    C1[(r0 + r) * ldc + c] = f2bf(acc[i][j][r]);
            }
        }
}

// ---------------- V transpose: Vt[b*1024 + v][s] = qkv[b*2048 + s][2048 + v]
__global__ __launch_bounds__(256) void vtrans_kernel(const unsigned short* __restrict__ qkv,
                                                     unsigned short* __restrict__ vt){
    __shared__ unsigned short tile[64][72];
    const int v0 = blockIdx.x * 64, s0 = blockIdx.y * 64, b = blockIdx.z;
    const int tx = threadIdx.x & 7, ty = threadIdx.x >> 3;   // ty 0..31
    for (int i = 0; i < 2; i++)
        *(int4*)&tile[ty + 32*i][tx * 8] =
            *(const int4*)(qkv + (size_t)(b * 2048 + s0 + ty + 32*i) * 3072 + 2048 + v0 + tx * 8);
    __syncthreads();
    for (int i = 0; i < 2; i++) {
        int v = ty + 32*i;
        int sl = tx * 8;
        ushort4 o0, o1;
        o0.x = tile[sl+0][v]; o0.y = tile[sl+1][v]; o0.z = tile[sl+2][v]; o0.w = tile[sl+3][v];
        o1.x = tile[sl+4][v]; o1.y = tile[sl+5][v]; o1.z = tile[sl+6][v]; o1.w = tile[sl+7][v];
        unsigned short* dst = vt + (size_t)(b * 1024 + v0 + v) * 2048 + s0 + sl;
        *(ushort4*)dst = o0; *(ushort4*)(dst + 4) = o1;
    }
}

// ---------------- MFMA flash attention, S^T form, no-max softmax, split-S x2,
// async K/V staging into XOR-swizzled 64x64 LDS arrays (128B rows, conflict-free reads).
// grid (S/128, NH, B*2): z = b*2 + chunk; chunk handles keys [ck*1024, +1024).
// qkv: [B*S][3072] bf16 (Q|K|V row-major); vt: [B*1024][2048] bf16 (V^T).
__global__ __launch_bounds__(256, 4) void flash7_kernel(
    const unsigned short* __restrict__ qkv,
    const unsigned short* __restrict__ vt,
    const float* __restrict__ biasT,
    unsigned short* __restrict__ ctxpb,   // [2][4096][1024] bf16 unnormalized
    float* __restrict__ rsbuf)            // [2][4096][16]  fp32 row sums
{
    const int qt = blockIdx.x, h = blockIdx.y;
    const int b = blockIdx.z >> 1, ck = blockIdx.z & 1;
    const int kt0 = ck << 10;
    const int t = threadIdx.x;
    const int w = t >> 6, lane = t & 63, quad = lane >> 4, l16 = lane & 15;
    const int q0 = qt * 128;

    __shared__ __align__(16) unsigned short Ks[64 * 64];     // [token j][dim], swizzled
    __shared__ __align__(16) unsigned short Vs[64 * 64];     // [dim d][token], swizzled
    __shared__ __align__(16) unsigned short Pb[128 * PST];   // P^T; Q scratch in prologue
    __shared__ float bias_s[192];

    // stage Q (128 x 64 bf16) into Pb scratch (stride PST)
    for (int s = 0; s < 4; s++) {
        int g = t + s * 256;
        int r = g >> 3, c = (g & 7) * 8;
        *(int4*)&Pb[r * PST + c] =
            *(const int4*)(qkv + (size_t)(b * S_LEN + q0 + r) * 3072 + h * 64 + c);
    }
    __syncthreads();
    bf16x8 qb[2][2];   // [ks][nt]
    for (int nt = 0; nt < 2; nt++)
        for (int ks = 0; ks < 2; ks++)
            qb[ks][nt] = *(const bf16x8*)&Pb[(w * 32 + nt * 16 + l16) * PST + ks * 32 + quad * 8];

    float rsum[2] = {0.f, 0.f};
    f32x4 ctx[4][2] = {};   // ctx^T: [d-tile nd][n-tile nt]

    const float* biasRow = biasT + h * NB_DELTA + 2047;

    // async staging: 2 passes per matrix; row = p*32 + w*8 + (lane>>3), granule remapped
    const int srow8 = lane >> 3;
    const int gg = (lane & 7) ^ srow8;
    const int swz = ((l16 & 7) * 8);   // read-side XOR base (row&7 == l16&7 for 16-row tiles)

    for (int kt = kt0; kt < kt0 + 1024; kt += 64) {
        __syncthreads();   // previous tile consumed (also protects Pb/Q overlay)
        {
            const unsigned short* kb = qkv + (size_t)(b * S_LEN + kt + w * 8 + srow8) * 3072 + 1024 + h * 64 + gg * 8;
            const unsigned short* vb = vt + (size_t)(b * 1024 + h * 64 + w * 8 + srow8) * 2048 + kt + gg * 8;
            gload16(kb,                         &Ks[(w * 8) * 64]);
            gload16(kb + (size_t)32 * 3072,     &Ks[(32 + w * 8) * 64]);
            gload16(vb,                         &Vs[(w * 8) * 64]);
            gload16(vb + (size_t)32 * 2048,     &Vs[(32 + w * 8) * 64]);
            if (t < 192) bias_s[t] = biasRow[kt - q0 - 127 + t] - 16.0f;
        }
        __syncthreads();

        // S^T = K Q^T : A = K rows (m=j), B = Q (n=q); each ka feeds both n-tiles
        f32x4 st[4][2] = {};
        for (int ks = 0; ks < 2; ks++)
            for (int nb = 0; nb < 4; nb++) {
                bf16x8 ka = *(const bf16x8*)&Ks[(nb * 16 + l16) * 64 + (((ks * 4 + quad) * 8) ^ swz)];
                st[nb][0] = __builtin_amdgcn_mfma_f32_16x16x32_bf16(ka, qb[ks][0], st[nb][0], 0, 0, 0);
                st[nb][1] = __builtin_amdgcn_mfma_f32_16x16x32_bf16(ka, qb[ks][1], st[nb][1], 0, 0, 0);
            }
        // bias + exp (lane-local rowsum), pack P^T
        for (int nt = 0; nt < 2; nt++) {
            const int ib = quad * 4 + 127 - w * 32 - nt * 16 - l16;
            float rs = 0.f;
            for (int nb = 0; nb < 4; nb++) {
                float e0 = __expf(st[nb][nt][0] + bias_s[ib + nb * 16 + 0]);
                float e1 = __expf(st[nb][nt][1] + bias_s[ib + nb * 16 + 1]);
                float e2 = __expf(st[nb][nt][2] + bias_s[ib + nb * 16 + 2]);
                float e3 = __expf(st[nb][nt][3] + bias_s[ib + nb * 16 + 3]);
                rs += (e0 + e1) + (e2 + e3);
                ushort4 pk;
                pk.x = f2bf_fast(e0); pk.y = f2bf_fast(e1);
                pk.z = f2bf_fast(e2); pk.w = f2bf_fast(e3);
                *(ushort4*)&Pb[(w * 32 + nt * 16 + l16) * PST + nb * 16 + quad * 4] = pk;
            }
            rsum[nt] += rs;
        }
        // ctx^T += Vt · P^T : each va feeds both n-tiles
        for (int ks = 0; ks < 2; ks++) {
            bf16x8 pb0 = *(const bf16x8*)&Pb[(w * 32 + l16) * PST + ks * 32 + quad * 8];
            bf16x8 pb1 = *(const bf16x8*)&Pb[(w * 32 + 16 + l16) * PST + ks * 32 + quad * 8];
            for (int nd = 0; nd < 4; nd++) {
                bf16x8 va = *(const bf16x8*)&Vs[(nd * 16 + l16) * 64 + (((ks * 4 + quad) * 8) ^ swz)];
                ctx[nd][0] = __builtin_amdgcn_mfma_f32_16x16x32_bf16(va, pb0, ctx[nd][0], 0, 0, 0);
                ctx[nd][1] = __builtin_amdgcn_mfma_f32_16x16x32_bf16(va, pb1, ctx[nd][1], 0, 0, 0);
            }
        }
    }
    // epilogue: store UNNORMALIZED bf16 partials + fp32 row sums
    unsigned short* cp = ctxpb + (size_t)ck * 4096 * 1024;
    for (int nt = 0; nt < 2; nt++) {
        float rs = rsum[nt];
        rs += __shfl_xor(rs, 16, 64);
        rs += __shfl_xor(rs, 32, 64);
        int row = b * S_LEN + q0 + w * 32 + nt * 16 + l16;
        if (quad == 0) rsbuf[((size_t)ck * 4096 + row) * 16 + h] = rs;
        for (int nd = 0; nd < 4; nd++) {
            ushort4 pk;
            pk.x = f2bf(ctx[nd][nt][0]); pk.y = f2bf(ctx[nd][nt][1]);
            pk.z = f2bf(ctx[nd][nt][2]); pk.w = f2bf(ctx[nd][nt][3]);
            *(ushort4*)&cp[(size_t)row * 1024 + h * 64 + nd * 16 + quad * 4] = pk;
        }
    }
}

// ---------------- combine: ctx_bf16 = (ctx0 + ctx1) / (l0 + l1)
__global__ __launch_bounds__(256) void combine_kernel(const unsigned short* __restrict__ ctxpb,
                                                      const float* __restrict__ rsbuf,
                                                      unsigned short* __restrict__ ctxb){
    int e = blockIdx.x * 256 + threadIdx.x;     // one ushort4 per thread
    int row = e >> 8;
    int c4 = (e & 255) * 4;
    int h = c4 >> 6;
    float l = rsbuf[(size_t)row * 16 + h] + rsbuf[((size_t)4096 + row) * 16 + h];
    ushort4 a  = *(const ushort4*)&ctxpb[(size_t)row * 1024 + c4];
    ushort4 b2 = *(const ushort4*)&ctxpb[(size_t)4096 * 1024 + (size_t)row * 1024 + c4];
    float inv = 1.f / l;
    ushort4 o;
    o.x = f2bf((bf2f(a.x) + bf2f(b2.x)) * inv);
    o.y = f2bf((bf2f(a.y) + bf2f(b2.y)) * inv);
    o.z = f2bf((bf2f(a.z) + bf2f(b2.z)) * inv);
    o.w = f2bf((bf2f(a.w) + bf2f(b2.w)) * inv);
    *(ushort4*)&ctxb[(size_t)row * 1024 + c4] = o;
}

extern "C" void kernel_launch(void* const* d_in, const int* in_sizes, int n_in,
                              void* d_out, int out_size, void* d_ws, size_t ws_size,
                              hipStream_t stream) {
    const float* hs       = (const float*)d_in[0];
    const float* Wq       = (const float*)d_in[1];
    const float* Wk       = (const float*)d_in[2];
    const float* Wv       = (const float*)d_in[3];
    const float* Wo       = (const float*)d_in[4];
    const float* rel_bias = (const float*)d_in[5];
    float* out = (float*)d_out;

    char* ws = (char*)d_ws;
    float* biasT          = (float*)ws;           ws += 262144;      // 16*4095*4 (+pad)
    unsigned short* hsb   = (unsigned short*)ws;  ws += 8388608;     // 4096x1024 bf16
    unsigned short* WT    = (unsigned short*)ws;  ws += 6291456;     // [Wq^T|Wk^T|Wv^T] 3072x1024
    unsigned short* WoT   = (unsigned short*)ws;  ws += 2097152;     // 1024x1024 bf16
    unsigned short* qkvb  = (unsigned short*)ws;  ws += 25165824;    // 4096x3072 bf16 (Q|K|V)
    unsigned short* Vtg   = (unsigned short*)ws;  ws += 8388608;     // 2048x2048 bf16
    unsigned short* ctxb  = (unsigned short*)ws;  ws += 8388608;     // 4096x1024 bf16
    unsigned short* ctxpb = (unsigned short*)ws;  ws += 16777216;    // 2 x 4096x1024 bf16
    float* rsbuf          = (float*)ws;                              // 2 x 4096x16 fp32

    prep_kernel<<<dim3(32, 32, 5), 256, 0, stream>>>(
        hs, hsb, Wq, Wk, Wv, Wo,
        WT, WT + 1024 * 1024, WT + 2 * 1024 * 1024, WoT, rel_bias, biasT);

    // Q|K|V projection, all row-major -> qkvb[4096][3072]
    gemm_bt_kernel<1, 128><<<dim3(24, 32), 256, 0, stream>>>(hsb, WT, nullptr, qkvb, 1024, 3072);
    // V transpose -> Vt[b*1024 + d][2048]
    vtrans_kernel<<<dim3(16, 32, 2), 256, 0, stream>>>(qkvb, Vtg);
    // attention, split-S x2
    flash7_kernel<<<dim3(S_LEN / 128, NH, 4), 256, 0, stream>>>(qkvb, Vtg, biasT, ctxpb, rsbuf);
    // combine partials -> bf16 ctx
    combine_kernel<<<4096, 256, 0, stream>>>(ctxpb, rsbuf, ctxb);
    // output projection -> fp32 (BM=64: 512 blocks, 2/CU)
    gemm_bt_kernel<0, 64><<<dim3(8, 64), 256, 0, stream>>>(ctxb, WoT, out, nullptr, 1024, 1024);
}